// Round 2
// baseline (467.479 us; speedup 1.0000x reference)
//
#include <hip/hip_runtime.h>
#include <cstdint>
#include <cstddef>

typedef unsigned short u16;
typedef __attribute__((ext_vector_type(8))) short short8;    // 8 bf16 (4 VGPRs) MFMA A/B frag (x32)
typedef __attribute__((ext_vector_type(4))) short short4v;   // 4 bf16 (2 VGPRs) MFMA A/B frag (x16)
typedef __attribute__((ext_vector_type(4))) float float4v;   // MFMA C/D frag
typedef __attribute__((ext_vector_type(4))) unsigned short ushort4v;

// ---------- helpers ----------
__device__ __forceinline__ u16 f2bf(float f) {
    union { float f; uint32_t u; } x; x.f = f;
    uint32_t r = x.u + 0x7fffu + ((x.u >> 16) & 1u);   // RTNE
    return (u16)(r >> 16);
}
__device__ __forceinline__ float bf2f(u16 b) {
    union { uint32_t u; float f; } x; x.u = ((uint32_t)b) << 16;
    return x.f;
}
// pack two fp32 -> two bf16 in one dword (round-to-nearest-away via +0x8000, then v_perm)
__device__ __forceinline__ uint32_t pack_bf16x2(float lo, float hi) {
    union { float f; uint32_t u; } a, b; a.f = lo; b.f = hi;
    return __builtin_amdgcn_perm(b.u + 0x8000u, a.u + 0x8000u, 0x07060302u);
}
// async global->LDS, 16B per lane; LDS dest must be wave-uniform base (HW adds lane*16)
__device__ __forceinline__ void gload_lds16(const u16* g, u16* l) {
    __builtin_amdgcn_global_load_lds(
        (const __attribute__((address_space(1))) void*)g,
        (__attribute__((address_space(3))) void*)l,
        16, 0, 0);
}

// ---------- 1. cast x (fp32 -> bf16), 4 elems/thread ----------
__global__ __launch_bounds__(256) void cast_x(const float4v* __restrict__ x,
                                              ushort4v* __restrict__ xb, int n4) {
    int i = blockIdx.x * 256 + threadIdx.x;
    if (i >= n4) return;
    float4v v = x[i];
    ushort4v o;
    #pragma unroll
    for (int j = 0; j < 4; ++j) o[j] = f2bf(v[j]);
    xb[i] = o;
}

// ---------- 2. transpose+cast weights: dst[n*2048+k] = src[k*Ns+n] ----------
__global__ __launch_bounds__(256) void transpose_cast(const float* __restrict__ src,
                                                      u16* __restrict__ dst, int Ns) {
    __shared__ float lds[32][33];
    const int tid = threadIdx.x;
    const int n0 = blockIdx.x * 32;
    const int k0 = blockIdx.y * 32;
    const int row = tid >> 3;            // k local
    const int c4  = (tid & 7) * 4;       // n local
    const float4v v = *(const float4v*)(src + (size_t)(k0 + row) * Ns + n0 + c4);
    #pragma unroll
    for (int i = 0; i < 4; ++i) lds[row][c4 + i] = v[i];
    __syncthreads();
    const int nrow = tid >> 3;           // n local
    const int k4   = (tid & 7) * 4;      // k local
    ushort4v o;
    #pragma unroll
    for (int i = 0; i < 4; ++i) o[i] = f2bf(lds[k4 + i][nrow]);
    *(ushort4v*)(dst + (size_t)(n0 + nrow) * 2048 + k0 + k4) = o;
}

// ---------- 3. GEMM: C[M,N] = A[M,K] * Bt[N,K]^T   (bf16 in, bf16/fp32 out) ----------
template<int WRITE_BF16>
__global__ __launch_bounds__(256) void gemm_bt(const u16* __restrict__ A,
                                               const u16* __restrict__ Bt,
                                               void* __restrict__ Cv,
                                               int M, int N, int K) {
    __shared__ u16 lds_a[128 * 32];
    __shared__ u16 lds_b[128 * 32];
    const int tid  = threadIdx.x;
    const int wave = tid >> 6;
    const int lane = tid & 63;
    const int quad = lane >> 4;
    const int l15  = lane & 15;
    const long m0 = (long)blockIdx.x * 128;
    const long n0 = (long)blockIdx.y * 128;
    const int wm = (wave >> 1) * 64;
    const int wn = (wave & 1) * 64;
    const int sa_row = lane >> 2;          // 0..15
    const int sa_col = (lane & 3) * 8;     // 0,8,16,24

    float4v acc[4][4];
    #pragma unroll
    for (int i = 0; i < 4; ++i)
        #pragma unroll
        for (int j = 0; j < 4; ++j)
            #pragma unroll
            for (int r = 0; r < 4; ++r) acc[i][j][r] = 0.0f;

    for (int k0 = 0; k0 < K; k0 += 32) {
        #pragma unroll
        for (int i = 0; i < 2; ++i) {
            const int slot = wave * 2 + i;          // 0..7, 16 rows each
            const u16* ga = A  + (m0 + slot * 16 + sa_row) * (long)K + k0 + sa_col;
            gload_lds16(ga, lds_a + slot * 512);
            const u16* gb = Bt + (n0 + slot * 16 + sa_row) * (long)K + k0 + sa_col;
            gload_lds16(gb, lds_b + slot * 512);
        }
        __syncthreads();
        short8 af[4], bfr[4];
        #pragma unroll
        for (int mt = 0; mt < 4; ++mt)
            af[mt] = *(const short8*)(lds_a + (wm + mt * 16 + l15) * 32 + quad * 8);
        #pragma unroll
        for (int nt = 0; nt < 4; ++nt)
            bfr[nt] = *(const short8*)(lds_b + (wn + nt * 16 + l15) * 32 + quad * 8);
        #pragma unroll
        for (int mt = 0; mt < 4; ++mt)
            #pragma unroll
            for (int nt = 0; nt < 4; ++nt)
                acc[mt][nt] = __builtin_amdgcn_mfma_f32_16x16x32_bf16(af[mt], bfr[nt], acc[mt][nt], 0, 0, 0);
        __syncthreads();
    }
    #pragma unroll
    for (int mt = 0; mt < 4; ++mt) {
        #pragma unroll
        for (int nt = 0; nt < 4; ++nt) {
            const long gr = m0 + wm + mt * 16 + quad * 4;
            const long gc = n0 + wn + nt * 16 + l15;
            #pragma unroll
            for (int r = 0; r < 4; ++r) {
                const float v = acc[mt][nt][r];
                if (WRITE_BF16) ((u16*)Cv)[(gr + r) * N + gc] = f2bf(v);
                else            ((float*)Cv)[(gr + r) * N + gc] = v;
            }
        }
    }
}

// ---------- 4. per-head RMSNorm + RoPE for Q,K (one wave per (token,head)) ----------
// Q gets softmax scale 1/8 AND log2(e) folded in (attention uses exp2).
__global__ __launch_bounds__(256) void norm_rope(const u16* __restrict__ qkv,
                                                 const float* __restrict__ qw,
                                                 const float* __restrict__ kw,
                                                 u16* __restrict__ Qr, u16* __restrict__ Kr) {
    const int W = blockIdx.x * 4 + (threadIdx.x >> 6);   // warp id, < 163840
    const int lane = threadIdx.x & 63;                   // = d
    const int token = W / 40;
    const int u = W - token * 40;                        // 0..31 Q head, 32..39 K head
    const int b = token >> 11;
    const int t = token & 2047;
    const bool isQ = (u < 32);
    const int col = isQ ? (u * 64 + lane) : (2048 + (u - 32) * 64 + lane);
    const float v = bf2f(qkv[(size_t)token * 3072 + col]);
    float ss = v * v;
    #pragma unroll
    for (int m = 1; m < 64; m <<= 1) ss += __shfl_xor(ss, m);
    const float rms = rsqrtf(ss * (1.0f / 64.0f) + 1e-5f);
    const float w = isQ ? qw[lane] : kw[lane];
    const float vn = v * rms * w;
    const float partner = __shfl_xor(vn, 32);
    const int i = lane & 31;
    const float invf = exp2f(-(float)i * (19.931568569324174f / 32.0f));
    const float ang = (float)t * invf;
    float sv, cv;
    sincosf(ang, &sv, &cv);
    float outv = vn * cv + ((lane < 32) ? -partner : partner) * sv;
    if (isQ) {
        outv *= 0.18033688011112042f;   // 0.125 * log2(e)
        Qr[(((size_t)b * 32 + u) * 2048 + t) * 64 + lane] = f2bf(outv);
    } else {
        Kr[(((size_t)b * 8 + (u - 32)) * 2048 + t) * 64 + lane] = f2bf(outv);
    }
}

// ---------- 5. V transpose: Vr[b][kh][d][t] ----------
__global__ __launch_bounds__(256) void v_transpose(const u16* __restrict__ qkv,
                                                   u16* __restrict__ Vr) {
    __shared__ u16 lds[32][36];
    const int tid = threadIdx.x;
    const int t0 = blockIdx.x * 32;
    const int d0 = blockIdx.y * 32;
    const int head = blockIdx.z;            // b*8+kh
    const int b = head >> 3, kh = head & 7;
    const int row = tid >> 3;               // t local
    const int c4  = (tid & 7) * 4;          // d local
    ushort4v val = *(const ushort4v*)(qkv + (size_t)(b * 2048 + t0 + row) * 3072
                                          + 2560 + kh * 64 + d0 + c4);
    #pragma unroll
    for (int i = 0; i < 4; ++i) lds[row][c4 + i] = val[i];
    __syncthreads();
    const int drow = tid >> 3;              // d local
    const int t4   = (tid & 7) * 4;         // t local
    ushort4v o;
    #pragma unroll
    for (int i = 0; i < 4; ++i) o[i] = lds[t4 + i][drow];
    *(ushort4v*)(Vr + ((size_t)head * 64 + d0 + drow) * 2048 + t0 + t4) = o;
}

// ---------- 6. flash attention, transposed dataflow (S^T / O^T) ----------
// S^T = K·Q^T via mfma_x32 (operand swap). S^T C/D layout (key=quad*4+r, qrow=l15)
// IS the B-operand layout of mfma_16x16x16_bf16, so PV (O^T = V^T·P^T) runs
// register-direct: no LDS round-trip for P. Softmax rows are lane-resident:
// 2 shuffles per reduction instead of 32; m/l/alpha are per-lane scalars.
#define KSTR 72    // lds_k row stride (d padded 64->72): frag reads 2-way max
#define VSTR 136   // lds_vt row stride (key padded 128->136): b64 frag reads 2-way max
__global__ __launch_bounds__(256) void attn_fwd(const u16* __restrict__ Qr,
                                                const u16* __restrict__ Kr,
                                                const u16* __restrict__ Vt,
                                                u16* __restrict__ Ob) {
    __shared__ u16 lds_k[128 * KSTR];
    __shared__ u16 lds_vt[64 * VSTR];
    const int tid  = threadIdx.x;
    const int wave = tid >> 6;
    const int lane = tid & 63;
    const int quad = lane >> 4;
    const int l15  = lane & 15;
    const int qx = gridDim.x - 1 - blockIdx.x;   // largest-work blocks first
    const int qt0 = qx * 64;
    const int bh = blockIdx.y;              // 0..63
    const int b = bh >> 5, h = bh & 31;
    const int kh = h >> 2;
    const u16* Qh = Qr + ((size_t)(b * 32 + h))  * 2048 * 64;
    const u16* Kh = Kr + ((size_t)(b * 8 + kh))  * 2048 * 64;
    const u16* Vh = Vt + ((size_t)(b * 8 + kh))  * 64 * 2048;

    // Q B-frags (n=l15=qrow, k=d=quad*8+j)
    const int qrow = qt0 + wave * 16 + l15;
    short8 qf[2];
    #pragma unroll
    for (int ks = 0; ks < 2; ++ks)
        qf[ks] = *(const short8*)(Qh + (size_t)qrow * 64 + ks * 32 + quad * 8);

    float m_i = -3e38f, l_i = 0.0f;         // per-lane: this lane's qrow
    float4v Oacc[4];                        // O^T: row=d=dt*16+quad*4+r, col=qrow=l15
    #pragma unroll
    for (int dt = 0; dt < 4; ++dt)
        #pragma unroll
        for (int r = 0; r < 4; ++r) Oacc[dt][r] = 0.0f;

    const int ktmax = qt0 >> 7;
    for (int kt = 0; kt <= ktmax; ++kt) {
        const int kt0 = kt << 7;
        // stage K tile 128x64 -> lds_k[key][d]
        #pragma unroll
        for (int j = 0; j < 4; ++j) {
            const int idx = j * 256 + tid;
            const int key = idx >> 3;
            const int d0  = (idx & 7) * 8;
            short8 v = *(const short8*)(Kh + (size_t)(kt0 + key) * 64 + d0);
            *(short8*)(lds_k + key * KSTR + d0) = v;
        }
        // stage V^T tile 64x128 -> lds_vt[d][key]
        #pragma unroll
        for (int j = 0; j < 4; ++j) {
            const int idx = j * 256 + tid;
            const int d  = idx >> 4;
            const int k8 = (idx & 15) * 8;
            short8 v = *(const short8*)(Vh + (size_t)d * 2048 + kt0 + k8);
            *(short8*)(lds_vt + d * VSTR + k8) = v;
        }
        __syncthreads();

        // S^T = K·Q^T : A=K frag (m=l15=key, k=d), B=Q frag
        float4v S[8];
        #pragma unroll
        for (int nt = 0; nt < 8; ++nt)
            #pragma unroll
            for (int r = 0; r < 4; ++r) S[nt][r] = 0.0f;
        #pragma unroll
        for (int ks = 0; ks < 2; ++ks)
            #pragma unroll
            for (int nt = 0; nt < 8; ++nt) {
                short8 kf = *(const short8*)(lds_k + (nt * 16 + l15) * KSTR + ks * 32 + quad * 8);
                S[nt] = __builtin_amdgcn_mfma_f32_16x16x32_bf16(kf, qf[ks], S[nt], 0, 0, 0);
            }
        // causal mask (diagonal tiles only): key = kt0+nt*16+quad*4+r vs this lane's qrow
        if (kt0 + 127 > qt0) {
            #pragma unroll
            for (int nt = 0; nt < 8; ++nt) {
                const int keyb = kt0 + nt * 16 + quad * 4;
                #pragma unroll
                for (int r = 0; r < 4; ++r)
                    if (keyb + r > qrow) S[nt][r] = -3e38f;
            }
        }
        // online softmax, lane-resident rows (values are in log2 domain)
        float mx = S[0][0];
        #pragma unroll
        for (int nt = 0; nt < 8; ++nt)
            #pragma unroll
            for (int r = 0; r < 4; ++r) mx = fmaxf(mx, S[nt][r]);
        mx = fmaxf(mx, __shfl_xor(mx, 16));
        mx = fmaxf(mx, __shfl_xor(mx, 32));
        const float mnew = fmaxf(m_i, mx);
        const float alpha = __builtin_amdgcn_exp2f(m_i - mnew);
        m_i = mnew;
        float rs = 0.0f;
        #pragma unroll
        for (int nt = 0; nt < 8; ++nt)
            #pragma unroll
            for (int r = 0; r < 4; ++r) {
                const float p = __builtin_amdgcn_exp2f(S[nt][r] - mnew);
                S[nt][r] = p;
                rs += p;
            }
        rs += __shfl_xor(rs, 16);
        rs += __shfl_xor(rs, 32);
        l_i = l_i * alpha + rs;
        #pragma unroll
        for (int dt = 0; dt < 4; ++dt)
            #pragma unroll
            for (int r = 0; r < 4; ++r) Oacc[dt][r] *= alpha;

        // O^T += V^T·P^T : P^T frag direct from S regs (B of x16), V^T frag from LDS (A)
        #pragma unroll
        for (int nt = 0; nt < 8; ++nt) {
            union { uint32_t u[2]; short4v s; } pu;
            pu.u[0] = pack_bf16x2(S[nt][0], S[nt][1]);
            pu.u[1] = pack_bf16x2(S[nt][2], S[nt][3]);
            const short4v pf = pu.s;
            #pragma unroll
            for (int dt = 0; dt < 4; ++dt) {
                const short4v vf = *(const short4v*)(lds_vt + (dt * 16 + l15) * VSTR + nt * 16 + quad * 4);
                Oacc[dt] = __builtin_amdgcn_mfma_f32_16x16x16bf16_1k(vf, pf, Oacc[dt], 0, 0, 0);
            }
        }
        __syncthreads();
    }
    // epilogue: O^T -> Ob[token][h*64+d], 8B store per (lane,dt)
    const float rl = 1.0f / l_i;
    #pragma unroll
    for (int dt = 0; dt < 4; ++dt) {
        ushort4v o;
        #pragma unroll
        for (int r = 0; r < 4; ++r) o[r] = f2bf(Oacc[dt][r] * rl);
        *(ushort4v*)(Ob + ((size_t)(b * 2048 + qrow)) * 2048 + h * 64 + dt * 16 + quad * 4) = o;
    }
}

// ---------- launcher ----------
extern "C" void kernel_launch(void* const* d_in, const int* in_sizes, int n_in,
                              void* d_out, int out_size, void* d_ws, size_t ws_size,
                              hipStream_t stream) {
    (void)in_sizes; (void)n_in; (void)out_size; (void)ws_size;
    const float* x  = (const float*)d_in[0];
    const float* Wq = (const float*)d_in[1];
    const float* Wk = (const float*)d_in[2];
    const float* Wv = (const float*)d_in[3];
    const float* Wo = (const float*)d_in[4];
    const float* qw = (const float*)d_in[5];
    const float* kw = (const float*)d_in[6];
    float* out = (float*)d_out;

    char* ws = (char*)d_ws;
    size_t off = 0;
    auto alloc = [&](size_t bytes) {
        char* p = ws + off;
        off += (bytes + 255) & ~(size_t)255;
        return p;
    };
    u16* xb     = (u16*)alloc((size_t)8388608 * 2);
    u16* wqkv_t = (u16*)alloc((size_t)3072 * 2048 * 2);
    u16* wo_t   = (u16*)alloc((size_t)2048 * 2048 * 2);
    u16* qkv    = (u16*)alloc((size_t)4096 * 3072 * 2);
    u16* q_r    = (u16*)alloc((size_t)2 * 32 * 2048 * 64 * 2);
    u16* k_r    = (u16*)alloc((size_t)2 * 8 * 2048 * 64 * 2);
    u16* v_r    = (u16*)alloc((size_t)2 * 8 * 64 * 2048 * 2);
    u16* attnb  = xb;   // reuse: xb dead after gemm1

    hipLaunchKernelGGL(cast_x, dim3(8192), dim3(256), 0, stream,
                       (const float4v*)x, (ushort4v*)xb, 2097152);
    hipLaunchKernelGGL(transpose_cast, dim3(64, 64), dim3(256), 0, stream, Wq, wqkv_t, 2048);
    hipLaunchKernelGGL(transpose_cast, dim3(16, 64), dim3(256), 0, stream, Wk, wqkv_t + (size_t)2048 * 2048, 512);
    hipLaunchKernelGGL(transpose_cast, dim3(16, 64), dim3(256), 0, stream, Wv, wqkv_t + (size_t)2560 * 2048, 512);
    hipLaunchKernelGGL(transpose_cast, dim3(64, 64), dim3(256), 0, stream, Wo, wo_t, 2048);
    hipLaunchKernelGGL(HIP_KERNEL_NAME(gemm_bt<1>), dim3(32, 24), dim3(256), 0, stream,
                       xb, wqkv_t, (void*)qkv, 4096, 3072, 2048);
    hipLaunchKernelGGL(norm_rope, dim3(40960), dim3(256), 0, stream, qkv, qw, kw, q_r, k_r);
    hipLaunchKernelGGL(v_transpose, dim3(64, 2, 16), dim3(256), 0, stream, qkv, v_r);
    hipLaunchKernelGGL(attn_fwd, dim3(32, 64), dim3(256), 0, stream, q_r, k_r, v_r, attnb);
    hipLaunchKernelGGL(HIP_KERNEL_NAME(gemm_bt<0>), dim3(32, 16), dim3(256), 0, stream,
                       attnb, wo_t, (void*)out, 4096, 2048, 2048);
}

// Round 3
// 399.620 us; speedup vs baseline: 1.1698x; 1.1698x over previous
//
#include <hip/hip_runtime.h>
#include <cstdint>
#include <cstddef>

typedef unsigned short u16;
typedef __attribute__((ext_vector_type(8))) short short8;    // 8 bf16 (4 VGPRs) MFMA A/B frag (x32)
typedef __attribute__((ext_vector_type(4))) short short4v;   // 4 bf16 (2 VGPRs) MFMA A/B frag (x16)
typedef __attribute__((ext_vector_type(4))) float float4v;   // MFMA C/D frag
typedef __attribute__((ext_vector_type(4))) unsigned short ushort4v;

// ---------- helpers ----------
__device__ __forceinline__ u16 f2bf(float f) {
    union { float f; uint32_t u; } x; x.f = f;
    uint32_t r = x.u + 0x7fffu + ((x.u >> 16) & 1u);   // RTNE
    return (u16)(r >> 16);
}
__device__ __forceinline__ float bf2f(u16 b) {
    union { uint32_t u; float f; } x; x.u = ((uint32_t)b) << 16;
    return x.f;
}
// pack two fp32 -> two bf16 in one dword
__device__ __forceinline__ uint32_t pack_bf16x2(float lo, float hi) {
    union { float f; uint32_t u; } a, b; a.f = lo; b.f = hi;
    return __builtin_amdgcn_perm(b.u + 0x8000u, a.u + 0x8000u, 0x07060302u);
}
// async global->LDS, 16B per lane; LDS dest must be wave-uniform base (HW adds lane*16)
__device__ __forceinline__ void gload_lds16(const u16* g, u16* l) {
    __builtin_amdgcn_global_load_lds(
        (const __attribute__((address_space(1))) void*)g,
        (__attribute__((address_space(3))) void*)l,
        16, 0, 0);
}

// ---------- 1. cast x (fp32 -> bf16), 4 elems/thread ----------
__global__ __launch_bounds__(256) void cast_x(const float4v* __restrict__ x,
                                              ushort4v* __restrict__ xb, int n4) {
    int i = blockIdx.x * 256 + threadIdx.x;
    if (i >= n4) return;
    float4v v = x[i];
    ushort4v o;
    #pragma unroll
    for (int j = 0; j < 4; ++j) o[j] = f2bf(v[j]);
    xb[i] = o;
}

// ---------- 2. transpose+cast weights: dst[n*2048+k] = src[k*Ns+n] ----------
__global__ __launch_bounds__(256) void transpose_cast(const float* __restrict__ src,
                                                      u16* __restrict__ dst, int Ns) {
    __shared__ float lds[32][33];
    const int tid = threadIdx.x;
    const int n0 = blockIdx.x * 32;
    const int k0 = blockIdx.y * 32;
    const int row = tid >> 3;            // k local
    const int c4  = (tid & 7) * 4;       // n local
    const float4v v = *(const float4v*)(src + (size_t)(k0 + row) * Ns + n0 + c4);
    #pragma unroll
    for (int i = 0; i < 4; ++i) lds[row][c4 + i] = v[i];
    __syncthreads();
    const int nrow = tid >> 3;           // n local
    const int k4   = (tid & 7) * 4;      // k local
    ushort4v o;
    #pragma unroll
    for (int i = 0; i < 4; ++i) o[i] = f2bf(lds[k4 + i][nrow]);
    *(ushort4v*)(dst + (size_t)(n0 + nrow) * 2048 + k0 + k4) = o;
}

// ---------- 3. GEMM: C[M,N] = A[M,K] * Bt[N,K]^T   (bf16 in, bf16/fp32 out) ----------
template<int WRITE_BF16>
__global__ __launch_bounds__(256) void gemm_bt(const u16* __restrict__ A,
                                               const u16* __restrict__ Bt,
                                               void* __restrict__ Cv,
                                               int M, int N, int K) {
    __shared__ u16 lds_a[128 * 32];
    __shared__ u16 lds_b[128 * 32];
    const int tid  = threadIdx.x;
    const int wave = tid >> 6;
    const int lane = tid & 63;
    const int quad = lane >> 4;
    const int l15  = lane & 15;
    const long m0 = (long)blockIdx.x * 128;
    const long n0 = (long)blockIdx.y * 128;
    const int wm = (wave >> 1) * 64;
    const int wn = (wave & 1) * 64;
    const int sa_row = lane >> 2;          // 0..15
    const int sa_col = (lane & 3) * 8;     // 0,8,16,24

    float4v acc[4][4];
    #pragma unroll
    for (int i = 0; i < 4; ++i)
        #pragma unroll
        for (int j = 0; j < 4; ++j)
            #pragma unroll
            for (int r = 0; r < 4; ++r) acc[i][j][r] = 0.0f;

    for (int k0 = 0; k0 < K; k0 += 32) {
        #pragma unroll
        for (int i = 0; i < 2; ++i) {
            const int slot = wave * 2 + i;          // 0..7, 16 rows each
            const u16* ga = A  + (m0 + slot * 16 + sa_row) * (long)K + k0 + sa_col;
            gload_lds16(ga, lds_a + slot * 512);
            const u16* gb = Bt + (n0 + slot * 16 + sa_row) * (long)K + k0 + sa_col;
            gload_lds16(gb, lds_b + slot * 512);
        }
        __syncthreads();
        short8 af[4], bfr[4];
        #pragma unroll
        for (int mt = 0; mt < 4; ++mt)
            af[mt] = *(const short8*)(lds_a + (wm + mt * 16 + l15) * 32 + quad * 8);
        #pragma unroll
        for (int nt = 0; nt < 4; ++nt)
            bfr[nt] = *(const short8*)(lds_b + (wn + nt * 16 + l15) * 32 + quad * 8);
        #pragma unroll
        for (int mt = 0; mt < 4; ++mt)
            #pragma unroll
            for (int nt = 0; nt < 4; ++nt)
                acc[mt][nt] = __builtin_amdgcn_mfma_f32_16x16x32_bf16(af[mt], bfr[nt], acc[mt][nt], 0, 0, 0);
        __syncthreads();
    }
    #pragma unroll
    for (int mt = 0; mt < 4; ++mt) {
        #pragma unroll
        for (int nt = 0; nt < 4; ++nt) {
            const long gr = m0 + wm + mt * 16 + quad * 4;
            const long gc = n0 + wn + nt * 16 + l15;
            #pragma unroll
            for (int r = 0; r < 4; ++r) {
                const float v = acc[mt][nt][r];
                if (WRITE_BF16) ((u16*)Cv)[(gr + r) * N + gc] = f2bf(v);
                else            ((float*)Cv)[(gr + r) * N + gc] = v;
            }
        }
    }
}

// ---------- 4. per-head RMSNorm + RoPE for Q,K ----------
// Q gets softmax scale 1/8 AND log2(e) folded in (attention uses exp2).
__global__ __launch_bounds__(256) void norm_rope(const u16* __restrict__ qkv,
                                                 const float* __restrict__ qw,
                                                 const float* __restrict__ kw,
                                                 u16* __restrict__ Qr, u16* __restrict__ Kr) {
    const int W = blockIdx.x * 4 + (threadIdx.x >> 6);   // warp id, < 163840
    const int lane = threadIdx.x & 63;                   // = d
    const int token = W / 40;
    const int u = W - token * 40;                        // 0..31 Q head, 32..39 K head
    const int b = token >> 11;
    const int t = token & 2047;
    const bool isQ = (u < 32);
    const int col = isQ ? (u * 64 + lane) : (2048 + (u - 32) * 64 + lane);
    const float v = bf2f(qkv[(size_t)token * 3072 + col]);
    float ss = v * v;
    #pragma unroll
    for (int m = 1; m < 64; m <<= 1) ss += __shfl_xor(ss, m);
    const float rms = rsqrtf(ss * (1.0f / 64.0f) + 1e-5f);
    const float w = isQ ? qw[lane] : kw[lane];
    const float vn = v * rms * w;
    const float partner = __shfl_xor(vn, 32);
    const int i = lane & 31;
    const float invf = exp2f(-(float)i * (19.931568569324174f / 32.0f));
    const float ang = (float)t * invf;
    float sv, cv;
    sincosf(ang, &sv, &cv);
    float outv = vn * cv + ((lane < 32) ? -partner : partner) * sv;
    if (isQ) {
        outv *= 0.18033688011112042f;   // 0.125 * log2(e)
        Qr[(((size_t)b * 32 + u) * 2048 + t) * 64 + lane] = f2bf(outv);
    } else {
        Kr[(((size_t)b * 8 + (u - 32)) * 2048 + t) * 64 + lane] = f2bf(outv);
    }
}

// ---------- 5. V transpose: Vr[b][kh][d][t] ----------
__global__ __launch_bounds__(256) void v_transpose(const u16* __restrict__ qkv,
                                                   u16* __restrict__ Vr) {
    __shared__ u16 lds[32][36];
    const int tid = threadIdx.x;
    const int t0 = blockIdx.x * 32;
    const int d0 = blockIdx.y * 32;
    const int head = blockIdx.z;            // b*8+kh
    const int b = head >> 3, kh = head & 7;
    const int row = tid >> 3;               // t local
    const int c4  = (tid & 7) * 4;          // d local
    ushort4v val = *(const ushort4v*)(qkv + (size_t)(b * 2048 + t0 + row) * 3072
                                          + 2560 + kh * 64 + d0 + c4);
    #pragma unroll
    for (int i = 0; i < 4; ++i) lds[row][c4 + i] = val[i];
    __syncthreads();
    const int drow = tid >> 3;              // d local
    const int t4   = (tid & 7) * 4;         // t local
    ushort4v o;
    #pragma unroll
    for (int i = 0; i < 4; ++i) o[i] = lds[t4 + i][drow];
    *(ushort4v*)(Vr + ((size_t)head * 64 + d0 + drow) * 2048 + t0 + t4) = o;
}

// ---------- 6. flash attention, transposed dataflow, software-pipelined ----------
// Q-tile 128 (8 waves x 16 rows), K-tile 128. Next tile prefetched into
// registers during compute of current tile -> global latency off critical path.
#define KSTR 72    // lds_k row stride (pad 64->72)
#define VSTR 136   // lds_vt row stride (pad 128->136)
__global__ __launch_bounds__(512, 4) void attn_fwd(const u16* __restrict__ Qr,
                                                   const u16* __restrict__ Kr,
                                                   const u16* __restrict__ Vt,
                                                   u16* __restrict__ Ob) {
    __shared__ u16 lds_k[128 * KSTR];
    __shared__ u16 lds_vt[64 * VSTR];
    const int tid  = threadIdx.x;
    const int wave = tid >> 6;              // 0..7
    const int lane = tid & 63;
    const int quad = lane >> 4;
    const int l15  = lane & 15;
    const int qx = gridDim.x - 1 - blockIdx.x;   // largest-work blocks first
    const int qt0 = qx * 128;
    const int bh = blockIdx.y;              // 0..63
    const int b = bh >> 5, h = bh & 31;
    const int kh = h >> 2;
    const u16* Qh = Qr + ((size_t)(b * 32 + h))  * 2048 * 64;
    const u16* Kh = Kr + ((size_t)(b * 8 + kh))  * 2048 * 64;
    const u16* Vh = Vt + ((size_t)(b * 8 + kh))  * 64 * 2048;

    // staging coords (512 threads, 2 x 16B each for K and V)
    const int k_key0 = tid >> 3;            // +64 for second chunk
    const int k_d0   = (tid & 7) * 8;
    const int v_d0   = tid >> 4;            // +32 for second chunk
    const int v_k8   = (tid & 15) * 8;

    // Q B-frags (n=l15=qrow, k=d=quad*8+j)
    const int qrow = qt0 + wave * 16 + l15;
    short8 qf[2];
    #pragma unroll
    for (int ks = 0; ks < 2; ++ks)
        qf[ks] = *(const short8*)(Qh + (size_t)qrow * 64 + ks * 32 + quad * 8);

    float m_i = -3e38f, l_i = 0.0f;
    float4v Oacc[4];                        // O^T: row=d=dt*16+quad*4+r, col=qrow=l15
    #pragma unroll
    for (int dt = 0; dt < 4; ++dt)
        #pragma unroll
        for (int r = 0; r < 4; ++r) Oacc[dt][r] = 0.0f;

    const int ktmax = qt0 >> 7;

    // prologue: prefetch tile 0
    short8 kreg[2], vreg[2];
    #pragma unroll
    for (int i = 0; i < 2; ++i) {
        kreg[i] = *(const short8*)(Kh + (size_t)(k_key0 + i * 64) * 64 + k_d0);
        vreg[i] = *(const short8*)(Vh + (size_t)(v_d0 + i * 32) * 2048 + v_k8);
    }

    for (int kt = 0; kt <= ktmax; ++kt) {
        const int kt0 = kt << 7;
        // write prefetched tile to LDS
        #pragma unroll
        for (int i = 0; i < 2; ++i) {
            *(short8*)(lds_k  + (k_key0 + i * 64) * KSTR + k_d0) = kreg[i];
            *(short8*)(lds_vt + (v_d0 + i * 32) * VSTR + v_k8)   = vreg[i];
        }
        __syncthreads();
        // prefetch next tile into regs (latency overlaps compute below)
        if (kt < ktmax) {
            const int nk0 = kt0 + 128;
            #pragma unroll
            for (int i = 0; i < 2; ++i) {
                kreg[i] = *(const short8*)(Kh + (size_t)(nk0 + k_key0 + i * 64) * 64 + k_d0);
                vreg[i] = *(const short8*)(Vh + (size_t)(v_d0 + i * 32) * 2048 + nk0 + v_k8);
            }
        }

        // S^T = K·Q^T : A=K frag (m=l15=key, k=d), B=Q frag
        float4v S[8];
        #pragma unroll
        for (int nt = 0; nt < 8; ++nt)
            #pragma unroll
            for (int r = 0; r < 4; ++r) S[nt][r] = 0.0f;
        #pragma unroll
        for (int ks = 0; ks < 2; ++ks)
            #pragma unroll
            for (int nt = 0; nt < 8; ++nt) {
                short8 kf = *(const short8*)(lds_k + (nt * 16 + l15) * KSTR + ks * 32 + quad * 8);
                S[nt] = __builtin_amdgcn_mfma_f32_16x16x32_bf16(kf, qf[ks], S[nt], 0, 0, 0);
            }
        // causal mask (diagonal tile only): key = kt0+nt*16+quad*4+r vs qrow
        if (kt == ktmax) {
            #pragma unroll
            for (int nt = 0; nt < 8; ++nt) {
                const int keyb = kt0 + nt * 16 + quad * 4;
                #pragma unroll
                for (int r = 0; r < 4; ++r)
                    if (keyb + r > qrow) S[nt][r] = -3e38f;
            }
        }
        // online softmax, lane-resident rows (log2 domain)
        float mx = S[0][0];
        #pragma unroll
        for (int nt = 0; nt < 8; ++nt)
            #pragma unroll
            for (int r = 0; r < 4; ++r) mx = fmaxf(mx, S[nt][r]);
        mx = fmaxf(mx, __shfl_xor(mx, 16));
        mx = fmaxf(mx, __shfl_xor(mx, 32));
        const float mnew = fmaxf(m_i, mx);
        const float alpha = __builtin_amdgcn_exp2f(m_i - mnew);
        m_i = mnew;
        float rs = 0.0f;
        #pragma unroll
        for (int nt = 0; nt < 8; ++nt)
            #pragma unroll
            for (int r = 0; r < 4; ++r) {
                const float p = __builtin_amdgcn_exp2f(S[nt][r] - mnew);
                S[nt][r] = p;
                rs += p;
            }
        rs += __shfl_xor(rs, 16);
        rs += __shfl_xor(rs, 32);
        l_i = l_i * alpha + rs;
        #pragma unroll
        for (int dt = 0; dt < 4; ++dt)
            #pragma unroll
            for (int r = 0; r < 4; ++r) Oacc[dt][r] *= alpha;

        // O^T += V^T·P^T : P^T frag direct from S regs (B of x16), V^T frag from LDS (A)
        #pragma unroll
        for (int nt = 0; nt < 8; ++nt) {
            union { uint32_t u[2]; short4v s; } pu;
            pu.u[0] = pack_bf16x2(S[nt][0], S[nt][1]);
            pu.u[1] = pack_bf16x2(S[nt][2], S[nt][3]);
            const short4v pf = pu.s;
            #pragma unroll
            for (int dt = 0; dt < 4; ++dt) {
                const short4v vf = *(const short4v*)(lds_vt + (dt * 16 + l15) * VSTR + nt * 16 + quad * 4);
                Oacc[dt] = __builtin_amdgcn_mfma_f32_16x16x16bf16_1k(vf, pf, Oacc[dt], 0, 0, 0);
            }
        }
        __syncthreads();
    }
    // epilogue: O^T -> Ob[token][h*64+d], 8B store per (lane,dt)
    const float rl = 1.0f / l_i;
    #pragma unroll
    for (int dt = 0; dt < 4; ++dt) {
        ushort4v o;
        #pragma unroll
        for (int r = 0; r < 4; ++r) o[r] = f2bf(Oacc[dt][r] * rl);
        *(ushort4v*)(Ob + ((size_t)(b * 2048 + qrow)) * 2048 + h * 64 + dt * 16 + quad * 4) = o;
    }
}

// ---------- launcher ----------
extern "C" void kernel_launch(void* const* d_in, const int* in_sizes, int n_in,
                              void* d_out, int out_size, void* d_ws, size_t ws_size,
                              hipStream_t stream) {
    (void)in_sizes; (void)n_in; (void)out_size; (void)ws_size;
    const float* x  = (const float*)d_in[0];
    const float* Wq = (const float*)d_in[1];
    const float* Wk = (const float*)d_in[2];
    const float* Wv = (const float*)d_in[3];
    const float* Wo = (const float*)d_in[4];
    const float* qw = (const float*)d_in[5];
    const float* kw = (const float*)d_in[6];
    float* out = (float*)d_out;

    char* ws = (char*)d_ws;
    size_t off = 0;
    auto alloc = [&](size_t bytes) {
        char* p = ws + off;
        off += (bytes + 255) & ~(size_t)255;
        return p;
    };
    u16* xb     = (u16*)alloc((size_t)8388608 * 2);
    u16* wqkv_t = (u16*)alloc((size_t)3072 * 2048 * 2);
    u16* wo_t   = (u16*)alloc((size_t)2048 * 2048 * 2);
    u16* qkv    = (u16*)alloc((size_t)4096 * 3072 * 2);
    u16* q_r    = (u16*)alloc((size_t)2 * 32 * 2048 * 64 * 2);
    u16* k_r    = (u16*)alloc((size_t)2 * 8 * 2048 * 64 * 2);
    u16* v_r    = (u16*)alloc((size_t)2 * 8 * 64 * 2048 * 2);
    u16* attnb  = xb;   // reuse: xb dead after gemm1

    hipLaunchKernelGGL(cast_x, dim3(8192), dim3(256), 0, stream,
                       (const float4v*)x, (ushort4v*)xb, 2097152);
    hipLaunchKernelGGL(transpose_cast, dim3(64, 64), dim3(256), 0, stream, Wq, wqkv_t, 2048);
    hipLaunchKernelGGL(transpose_cast, dim3(16, 64), dim3(256), 0, stream, Wk, wqkv_t + (size_t)2048 * 2048, 512);
    hipLaunchKernelGGL(transpose_cast, dim3(16, 64), dim3(256), 0, stream, Wv, wqkv_t + (size_t)2560 * 2048, 512);
    hipLaunchKernelGGL(transpose_cast, dim3(64, 64), dim3(256), 0, stream, Wo, wo_t, 2048);
    hipLaunchKernelGGL(HIP_KERNEL_NAME(gemm_bt<1>), dim3(32, 24), dim3(256), 0, stream,
                       xb, wqkv_t, (void*)qkv, 4096, 3072, 2048);
    hipLaunchKernelGGL(norm_rope, dim3(40960), dim3(256), 0, stream, qkv, qw, kw, q_r, k_r);
    hipLaunchKernelGGL(v_transpose, dim3(64, 2, 16), dim3(256), 0, stream, qkv, v_r);
    hipLaunchKernelGGL(attn_fwd, dim3(16, 64), dim3(512), 0, stream, q_r, k_r, v_r, attnb);
    hipLaunchKernelGGL(HIP_KERNEL_NAME(gemm_bt<0>), dim3(32, 16), dim3(256), 0, stream,
                       attnb, wo_t, (void*)out, 4096, 2048, 2048);
}

// Round 4
// 344.158 us; speedup vs baseline: 1.3583x; 1.1612x over previous
//
#include <hip/hip_runtime.h>
#include <cstdint>
#include <cstddef>

typedef unsigned short u16;
typedef __attribute__((ext_vector_type(8))) short short8;    // 8 bf16 (4 VGPRs) MFMA A/B frag (x32)
typedef __attribute__((ext_vector_type(4))) short short4v;   // 4 bf16 (2 VGPRs) MFMA A/B frag (x16)
typedef __attribute__((ext_vector_type(4))) float float4v;   // MFMA C/D frag
typedef __attribute__((ext_vector_type(4))) unsigned short ushort4v;
typedef __attribute__((ext_vector_type(2))) float float2v;

// ---------- helpers ----------
__device__ __forceinline__ u16 f2bf(float f) {
    union { float f; uint32_t u; } x; x.f = f;
    uint32_t r = x.u + 0x7fffu + ((x.u >> 16) & 1u);   // RTNE
    return (u16)(r >> 16);
}
__device__ __forceinline__ float bf2f(u16 b) {
    union { uint32_t u; float f; } x; x.u = ((uint32_t)b) << 16;
    return x.f;
}
// pack two fp32 -> two bf16 in one dword
__device__ __forceinline__ uint32_t pack_bf16x2(float lo, float hi) {
    union { float f; uint32_t u; } a, b; a.f = lo; b.f = hi;
    return __builtin_amdgcn_perm(b.u + 0x8000u, a.u + 0x8000u, 0x07060302u);
}
// async global->LDS, 16B per lane; LDS dest must be wave-uniform base (HW adds lane*16)
__device__ __forceinline__ void gload_lds16(const u16* g, u16* l) {
    __builtin_amdgcn_global_load_lds(
        (const __attribute__((address_space(1))) void*)g,
        (__attribute__((address_space(3))) void*)l,
        16, 0, 0);
}

// ---------- 1. cast x (fp32 -> bf16), 4 elems/thread ----------
__global__ __launch_bounds__(256) void cast_x(const float4v* __restrict__ x,
                                              ushort4v* __restrict__ xb, int n4) {
    int i = blockIdx.x * 256 + threadIdx.x;
    if (i >= n4) return;
    float4v v = x[i];
    ushort4v o;
    #pragma unroll
    for (int j = 0; j < 4; ++j) o[j] = f2bf(v[j]);
    xb[i] = o;
}

// ---------- 2. transpose+cast weights: dst[n*2048+k] = src[k*Ns+n] ----------
__global__ __launch_bounds__(256) void transpose_cast(const float* __restrict__ src,
                                                      u16* __restrict__ dst, int Ns) {
    __shared__ float lds[32][33];
    const int tid = threadIdx.x;
    const int n0 = blockIdx.x * 32;
    const int k0 = blockIdx.y * 32;
    const int row = tid >> 3;            // k local
    const int c4  = (tid & 7) * 4;       // n local
    const float4v v = *(const float4v*)(src + (size_t)(k0 + row) * Ns + n0 + c4);
    #pragma unroll
    for (int i = 0; i < 4; ++i) lds[row][c4 + i] = v[i];
    __syncthreads();
    const int nrow = tid >> 3;           // n local
    const int k4   = (tid & 7) * 4;      // k local
    ushort4v o;
    #pragma unroll
    for (int i = 0; i < 4; ++i) o[i] = f2bf(lds[k4 + i][nrow]);
    *(ushort4v*)(dst + (size_t)(n0 + nrow) * 2048 + k0 + k4) = o;
}

// ---------- 3. GEMM: C[M,N] = A[M,K] * Bt[N,K]^T   (bf16 in, bf16/fp32 out) ----------
template<int WRITE_BF16>
__global__ __launch_bounds__(256) void gemm_bt(const u16* __restrict__ A,
                                               const u16* __restrict__ Bt,
                                               void* __restrict__ Cv,
                                               int M, int N, int K) {
    __shared__ u16 lds_a[128 * 32];
    __shared__ u16 lds_b[128 * 32];
    const int tid  = threadIdx.x;
    const int wave = tid >> 6;
    const int lane = tid & 63;
    const int quad = lane >> 4;
    const int l15  = lane & 15;
    const long m0 = (long)blockIdx.x * 128;
    const long n0 = (long)blockIdx.y * 128;
    const int wm = (wave >> 1) * 64;
    const int wn = (wave & 1) * 64;
    const int sa_row = lane >> 2;          // 0..15
    const int sa_col = (lane & 3) * 8;     // 0,8,16,24

    float4v acc[4][4];
    #pragma unroll
    for (int i = 0; i < 4; ++i)
        #pragma unroll
        for (int j = 0; j < 4; ++j)
            #pragma unroll
            for (int r = 0; r < 4; ++r) acc[i][j][r] = 0.0f;

    for (int k0 = 0; k0 < K; k0 += 32) {
        #pragma unroll
        for (int i = 0; i < 2; ++i) {
            const int slot = wave * 2 + i;          // 0..7, 16 rows each
            const u16* ga = A  + (m0 + slot * 16 + sa_row) * (long)K + k0 + sa_col;
            gload_lds16(ga, lds_a + slot * 512);
            const u16* gb = Bt + (n0 + slot * 16 + sa_row) * (long)K + k0 + sa_col;
            gload_lds16(gb, lds_b + slot * 512);
        }
        __syncthreads();
        short8 af[4], bfr[4];
        #pragma unroll
        for (int mt = 0; mt < 4; ++mt)
            af[mt] = *(const short8*)(lds_a + (wm + mt * 16 + l15) * 32 + quad * 8);
        #pragma unroll
        for (int nt = 0; nt < 4; ++nt)
            bfr[nt] = *(const short8*)(lds_b + (wn + nt * 16 + l15) * 32 + quad * 8);
        #pragma unroll
        for (int mt = 0; mt < 4; ++mt)
            #pragma unroll
            for (int nt = 0; nt < 4; ++nt)
                acc[mt][nt] = __builtin_amdgcn_mfma_f32_16x16x32_bf16(af[mt], bfr[nt], acc[mt][nt], 0, 0, 0);
        __syncthreads();
    }
    #pragma unroll
    for (int mt = 0; mt < 4; ++mt) {
        #pragma unroll
        for (int nt = 0; nt < 4; ++nt) {
            const long gr = m0 + wm + mt * 16 + quad * 4;
            const long gc = n0 + wn + nt * 16 + l15;
            #pragma unroll
            for (int r = 0; r < 4; ++r) {
                const float v = acc[mt][nt][r];
                if (WRITE_BF16) ((u16*)Cv)[(gr + r) * N + gc] = f2bf(v);
                else            ((float*)Cv)[(gr + r) * N + gc] = v;
            }
        }
    }
}

// ---------- 4a. RoPE cos/sin table: tab[t*32+i] = (cos, sin)(t * invf(i)) ----------
__global__ __launch_bounds__(256) void rope_table(float2v* __restrict__ tab) {
    const int idx = blockIdx.x * 256 + threadIdx.x;   // 65536
    const int t = idx >> 5;
    const int i = idx & 31;
    const float invf = exp2f(-(float)i * (19.931568569324174f / 32.0f));
    float sv, cv;
    sincosf((float)t * invf, &sv, &cv);
    float2v o; o[0] = cv; o[1] = sv;
    tab[idx] = o;
}

// ---------- 4b. per-head RMSNorm + RoPE for Q,K ----------
// Q gets softmax scale 1/8 AND log2(e) folded in (attention uses exp2).
__global__ __launch_bounds__(256) void norm_rope(const u16* __restrict__ qkv,
                                                 const float* __restrict__ qw,
                                                 const float* __restrict__ kw,
                                                 const float2v* __restrict__ tab,
                                                 u16* __restrict__ Qr, u16* __restrict__ Kr) {
    const int W = blockIdx.x * 4 + (threadIdx.x >> 6);   // warp id, < 163840
    const int lane = threadIdx.x & 63;                   // = d
    const int token = W / 40;
    const int u = W - token * 40;                        // 0..31 Q head, 32..39 K head
    const int b = token >> 11;
    const int t = token & 2047;
    const bool isQ = (u < 32);
    const int col = isQ ? (u * 64 + lane) : (2048 + (u - 32) * 64 + lane);
    const float v = bf2f(qkv[(size_t)token * 3072 + col]);
    float ss = v * v;
    #pragma unroll
    for (int m = 1; m < 64; m <<= 1) ss += __shfl_xor(ss, m);
    const float rms = rsqrtf(ss * (1.0f / 64.0f) + 1e-5f);
    const float w = isQ ? qw[lane] : kw[lane];
    const float vn = v * rms * w;
    const float partner = __shfl_xor(vn, 32);
    const float2v cs = tab[t * 32 + (lane & 31)];
    float outv = vn * cs[0] + ((lane < 32) ? -partner : partner) * cs[1];
    if (isQ) {
        outv *= 0.18033688011112042f;   // 0.125 * log2(e)
        Qr[(((size_t)b * 32 + u) * 2048 + t) * 64 + lane] = f2bf(outv);
    } else {
        Kr[(((size_t)b * 8 + (u - 32)) * 2048 + t) * 64 + lane] = f2bf(outv);
    }
}

// ---------- 5. V transpose: Vr[b][kh][d][t] ----------
__global__ __launch_bounds__(256) void v_transpose(const u16* __restrict__ qkv,
                                                   u16* __restrict__ Vr) {
    __shared__ u16 lds[32][36];
    const int tid = threadIdx.x;
    const int t0 = blockIdx.x * 32;
    const int d0 = blockIdx.y * 32;
    const int head = blockIdx.z;            // b*8+kh
    const int b = head >> 3, kh = head & 7;
    const int row = tid >> 3;               // t local
    const int c4  = (tid & 7) * 4;          // d local
    ushort4v val = *(const ushort4v*)(qkv + (size_t)(b * 2048 + t0 + row) * 3072
                                          + 2560 + kh * 64 + d0 + c4);
    #pragma unroll
    for (int i = 0; i < 4; ++i) lds[row][c4 + i] = val[i];
    __syncthreads();
    const int drow = tid >> 3;              // d local
    const int t4   = (tid & 7) * 4;         // t local
    ushort4v o;
    #pragma unroll
    for (int i = 0; i < 4; ++i) o[i] = lds[t4 + i][drow];
    *(ushort4v*)(Vr + ((size_t)head * 64 + d0 + drow) * 2048 + t0 + t4) = o;
}

// ---------- 6. flash attention: folded causal triangle + LDS double-buffer ----------
// Each block processes TWO q-tiles (qxA = 15-bx, qxB = bx) -> uniform 17
// tile-iters per block, 512 blocks, all resident, no drain tail. LDS is
// double-buffered with a single barrier per iter: compute from buf[p] while
// the register-prefetch for tile i+1 is written to buf[1-p]. Phase switch
// resets m/l; alpha=exp2(-inf)=0 auto-zeroes the O accumulator.
#define KSTR 72    // lds_k row stride (pad 64->72)
#define VSTR 136   // lds_vt row stride (pad 128->136)
__global__ __launch_bounds__(512, 4) void attn_fwd(const u16* __restrict__ Qr,
                                                   const u16* __restrict__ Kr,
                                                   const u16* __restrict__ Vt,
                                                   u16* __restrict__ Ob) {
    __shared__ u16 lds_k[2][128 * KSTR];
    __shared__ u16 lds_vt[2][64 * VSTR];
    const int tid  = threadIdx.x;
    const int wave = tid >> 6;              // 0..7
    const int lane = tid & 63;
    const int quad = lane >> 4;
    const int l15  = lane & 15;
    const int qxB = blockIdx.x;             // 0..7
    const int qxA = 15 - qxB;               // 15..8
    const int bh = blockIdx.y;              // 0..63
    const int b = bh >> 5, h = bh & 31;
    const int kh = h >> 2;
    const u16* Qh = Qr + ((size_t)(b * 32 + h))  * 2048 * 64;
    const u16* Kh = Kr + ((size_t)(b * 8 + kh))  * 2048 * 64;
    const u16* Vh = Vt + ((size_t)(b * 8 + kh))  * 64 * 2048;

    // staging coords (512 threads, 2 x 16B each for K and V)
    const int k_key0 = tid >> 3;            // +64 for second chunk
    const int k_d0   = (tid & 7) * 8;
    const int v_d0   = tid >> 4;            // +32 for second chunk
    const int v_k8   = (tid & 15) * 8;

    // Q B-frags for both phases (n=l15=qrow, k=d=quad*8+j)
    const int qrowA = qxA * 128 + wave * 16 + l15;
    const int qrowB = qxB * 128 + wave * 16 + l15;
    short8 qfA[2], qfB[2];
    #pragma unroll
    for (int ks = 0; ks < 2; ++ks) {
        qfA[ks] = *(const short8*)(Qh + (size_t)qrowA * 64 + ks * 32 + quad * 8);
        qfB[ks] = *(const short8*)(Qh + (size_t)qrowB * 64 + ks * 32 + quad * 8);
    }
    short8 qf0 = qfA[0], qf1 = qfA[1];
    int qrow_cur = qrowA;

    float m_i = -3e38f, l_i = 0.0f;
    float4v Oacc[4];                        // O^T: row=d=dt*16+quad*4+r, col=qrow=l15
    #pragma unroll
    for (int dt = 0; dt < 4; ++dt)
        #pragma unroll
        for (int r = 0; r < 4; ++r) Oacc[dt][r] = 0.0f;

    // prologue: load tile kt=0 (phase A) into regs, write buf 0
    short8 kreg[2], vreg[2];
    #pragma unroll
    for (int i = 0; i < 2; ++i) {
        kreg[i] = *(const short8*)(Kh + (size_t)(k_key0 + i * 64) * 64 + k_d0);
        vreg[i] = *(const short8*)(Vh + (size_t)(v_d0 + i * 32) * 2048 + v_k8);
    }
    #pragma unroll
    for (int i = 0; i < 2; ++i) {
        *(short8*)(lds_k[0]  + (k_key0 + i * 64) * KSTR + k_d0) = kreg[i];
        *(short8*)(lds_vt[0] + (v_d0 + i * 32) * VSTR + v_k8)   = vreg[i];
    }
    __syncthreads();

    const int n_it = 17;                    // (qxA+1) + (qxB+1) always 17
    for (int i = 0; i < n_it; ++i) {
        const int p = i & 1;
        const bool last = (i == n_it - 1);
        const int kt_cur = (i <= qxA) ? i : (i - qxA - 1);
        const int kt0 = kt_cur << 7;

        // prefetch next tile into regs (latency overlaps compute)
        if (!last) {
            const int ip1 = i + 1;
            const int ktn = (ip1 <= qxA) ? ip1 : (ip1 - qxA - 1);
            const size_t nk0 = (size_t)(ktn << 7);
            #pragma unroll
            for (int j = 0; j < 2; ++j) {
                kreg[j] = *(const short8*)(Kh + (nk0 + k_key0 + j * 64) * 64 + k_d0);
                vreg[j] = *(const short8*)(Vh + (size_t)(v_d0 + j * 32) * 2048 + nk0 + v_k8);
            }
        }

        // S^T = K·Q^T : A=K frag (m=l15=key, k=d), B=Q frag
        float4v S[8];
        #pragma unroll
        for (int nt = 0; nt < 8; ++nt)
            #pragma unroll
            for (int r = 0; r < 4; ++r) S[nt][r] = 0.0f;
        #pragma unroll
        for (int ks = 0; ks < 2; ++ks) {
            const short8 qf = ks ? qf1 : qf0;
            #pragma unroll
            for (int nt = 0; nt < 8; ++nt) {
                short8 kf = *(const short8*)(lds_k[p] + (nt * 16 + l15) * KSTR + ks * 32 + quad * 8);
                S[nt] = __builtin_amdgcn_mfma_f32_16x16x32_bf16(kf, qf, S[nt], 0, 0, 0);
            }
        }
        // causal mask on the diagonal tile of each phase
        if (i == qxA || last) {
            #pragma unroll
            for (int nt = 0; nt < 8; ++nt) {
                const int keyb = kt0 + nt * 16 + quad * 4;
                #pragma unroll
                for (int r = 0; r < 4; ++r)
                    if (keyb + r > qrow_cur) S[nt][r] = -3e38f;
            }
        }
        // online softmax, lane-resident rows (log2 domain)
        float mx = S[0][0];
        #pragma unroll
        for (int nt = 0; nt < 8; ++nt)
            #pragma unroll
            for (int r = 0; r < 4; ++r) mx = fmaxf(mx, S[nt][r]);
        mx = fmaxf(mx, __shfl_xor(mx, 16));
        mx = fmaxf(mx, __shfl_xor(mx, 32));
        const float mnew = fmaxf(m_i, mx);
        const float alpha = __builtin_amdgcn_exp2f(m_i - mnew);
        m_i = mnew;
        float rs = 0.0f;
        #pragma unroll
        for (int nt = 0; nt < 8; ++nt)
            #pragma unroll
            for (int r = 0; r < 4; ++r) {
                const float pv = __builtin_amdgcn_exp2f(S[nt][r] - mnew);
                S[nt][r] = pv;
                rs += pv;
            }
        rs += __shfl_xor(rs, 16);
        rs += __shfl_xor(rs, 32);
        l_i = l_i * alpha + rs;
        #pragma unroll
        for (int dt = 0; dt < 4; ++dt)
            #pragma unroll
            for (int r = 0; r < 4; ++r) Oacc[dt][r] *= alpha;

        // O^T += V^T·P^T : P^T frag direct from S regs (B of x16), V^T frag from LDS (A)
        #pragma unroll
        for (int nt = 0; nt < 8; ++nt) {
            union { uint32_t u[2]; short4v s; } pu;
            pu.u[0] = pack_bf16x2(S[nt][0], S[nt][1]);
            pu.u[1] = pack_bf16x2(S[nt][2], S[nt][3]);
            const short4v pf = pu.s;
            #pragma unroll
            for (int dt = 0; dt < 4; ++dt) {
                const short4v vf = *(const short4v*)(lds_vt[p] + (dt * 16 + l15) * VSTR + nt * 16 + quad * 4);
                Oacc[dt] = __builtin_amdgcn_mfma_f32_16x16x16bf16_1k(vf, pf, Oacc[dt], 0, 0, 0);
            }
        }

        // phase A -> B switch: write A's output, reset stats (alpha=0 zeroes Oacc)
        if (i == qxA) {
            const float rl = 1.0f / l_i;
            #pragma unroll
            for (int dt = 0; dt < 4; ++dt) {
                ushort4v o;
                #pragma unroll
                for (int r = 0; r < 4; ++r) o[r] = f2bf(Oacc[dt][r] * rl);
                *(ushort4v*)(Ob + ((size_t)(b * 2048 + qrowA)) * 2048 + h * 64 + dt * 16 + quad * 4) = o;
            }
            m_i = -3e38f;
            l_i = 0.0f;
            qf0 = qfB[0];
            qf1 = qfB[1];
            qrow_cur = qrowB;
        }

        // write prefetched regs into the other buffer; single barrier per iter
        if (!last) {
            #pragma unroll
            for (int j = 0; j < 2; ++j) {
                *(short8*)(lds_k[1 - p]  + (k_key0 + j * 64) * KSTR + k_d0) = kreg[j];
                *(short8*)(lds_vt[1 - p] + (v_d0 + j * 32) * VSTR + v_k8)   = vreg[j];
            }
        }
        __syncthreads();
    }
    // final epilogue: phase B output
    const float rl = 1.0f / l_i;
    #pragma unroll
    for (int dt = 0; dt < 4; ++dt) {
        ushort4v o;
        #pragma unroll
        for (int r = 0; r < 4; ++r) o[r] = f2bf(Oacc[dt][r] * rl);
        *(ushort4v*)(Ob + ((size_t)(b * 2048 + qrowB)) * 2048 + h * 64 + dt * 16 + quad * 4) = o;
    }
}

// ---------- launcher ----------
extern "C" void kernel_launch(void* const* d_in, const int* in_sizes, int n_in,
                              void* d_out, int out_size, void* d_ws, size_t ws_size,
                              hipStream_t stream) {
    (void)in_sizes; (void)n_in; (void)out_size; (void)ws_size;
    const float* x  = (const float*)d_in[0];
    const float* Wq = (const float*)d_in[1];
    const float* Wk = (const float*)d_in[2];
    const float* Wv = (const float*)d_in[3];
    const float* Wo = (const float*)d_in[4];
    const float* qw = (const float*)d_in[5];
    const float* kw = (const float*)d_in[6];
    float* out = (float*)d_out;

    char* ws = (char*)d_ws;
    size_t off = 0;
    auto alloc = [&](size_t bytes) {
        char* p = ws + off;
        off += (bytes + 255) & ~(size_t)255;
        return p;
    };
    u16* xb     = (u16*)alloc((size_t)8388608 * 2);
    u16* wqkv_t = (u16*)alloc((size_t)3072 * 2048 * 2);
    u16* wo_t   = (u16*)alloc((size_t)2048 * 2048 * 2);
    u16* qkv    = (u16*)alloc((size_t)4096 * 3072 * 2);
    u16* q_r    = (u16*)alloc((size_t)2 * 32 * 2048 * 64 * 2);
    u16* k_r    = (u16*)alloc((size_t)2 * 8 * 2048 * 64 * 2);
    u16* v_r    = (u16*)alloc((size_t)2 * 8 * 64 * 2048 * 2);
    float2v* rtab = (float2v*)alloc((size_t)2048 * 32 * 8);   // 512 KB
    u16* attnb  = xb;   // reuse: xb dead after gemm1

    hipLaunchKernelGGL(cast_x, dim3(8192), dim3(256), 0, stream,
                       (const float4v*)x, (ushort4v*)xb, 2097152);
    hipLaunchKernelGGL(rope_table, dim3(256), dim3(256), 0, stream, rtab);
    hipLaunchKernelGGL(transpose_cast, dim3(64, 64), dim3(256), 0, stream, Wq, wqkv_t, 2048);
    hipLaunchKernelGGL(transpose_cast, dim3(16, 64), dim3(256), 0, stream, Wk, wqkv_t + (size_t)2048 * 2048, 512);
    hipLaunchKernelGGL(transpose_cast, dim3(16, 64), dim3(256), 0, stream, Wv, wqkv_t + (size_t)2560 * 2048, 512);
    hipLaunchKernelGGL(transpose_cast, dim3(64, 64), dim3(256), 0, stream, Wo, wo_t, 2048);
    hipLaunchKernelGGL(HIP_KERNEL_NAME(gemm_bt<1>), dim3(32, 24), dim3(256), 0, stream,
                       xb, wqkv_t, (void*)qkv, 4096, 3072, 2048);
    hipLaunchKernelGGL(norm_rope, dim3(40960), dim3(256), 0, stream, qkv, qw, kw, rtab, q_r, k_r);
    hipLaunchKernelGGL(v_transpose, dim3(64, 2, 16), dim3(256), 0, stream, qkv, v_r);
    hipLaunchKernelGGL(attn_fwd, dim3(8, 64), dim3(512), 0, stream, q_r, k_r, v_r, attnb);
    hipLaunchKernelGGL(HIP_KERNEL_NAME(gemm_bt<0>), dim3(32, 16), dim3(256), 0, stream,
                       attnb, wo_t, (void*)out, 4096, 2048, 2048);
}

// Round 5
// 331.060 us; speedup vs baseline: 1.4121x; 1.0396x over previous
//
#include <hip/hip_runtime.h>
#include <cstdint>
#include <cstddef>

typedef unsigned short u16;
typedef __attribute__((ext_vector_type(8))) short short8;    // 8 bf16 (4 VGPRs) MFMA A/B frag (x32)
typedef __attribute__((ext_vector_type(4))) short short4v;   // 4 bf16 (2 VGPRs) MFMA A/B frag (x16)
typedef __attribute__((ext_vector_type(4))) float float4v;   // MFMA C/D frag
typedef __attribute__((ext_vector_type(4))) unsigned short ushort4v;
typedef __attribute__((ext_vector_type(2))) float float2v;

// ---------- helpers ----------
__device__ __forceinline__ u16 f2bf(float f) {
    union { float f; uint32_t u; } x; x.f = f;
    uint32_t r = x.u + 0x7fffu + ((x.u >> 16) & 1u);   // RTNE
    return (u16)(r >> 16);
}
__device__ __forceinline__ float bf2f(u16 b) {
    union { uint32_t u; float f; } x; x.u = ((uint32_t)b) << 16;
    return x.f;
}
// pack two fp32 -> two bf16 in one dword
__device__ __forceinline__ uint32_t pack_bf16x2(float lo, float hi) {
    union { float f; uint32_t u; } a, b; a.f = lo; b.f = hi;
    return __builtin_amdgcn_perm(b.u + 0x8000u, a.u + 0x8000u, 0x07060302u);
}
// async global->LDS, 16B per lane; LDS dest must be wave-uniform base (HW adds lane*16)
__device__ __forceinline__ void gload_lds16(const u16* g, u16* l) {
    __builtin_amdgcn_global_load_lds(
        (const __attribute__((address_space(1))) void*)g,
        (__attribute__((address_space(3))) void*)l,
        16, 0, 0);
}

// ---------- 1. merged prep: cast x, rope table, weight transposes ----------
// blocks [0,8192): cast x fp32->bf16 (4 elem/thread)
// blocks [8192,8448): rope cos/sin table tab[t*32+i]
// blocks [8448,14592): Wq|Wk|Wv transpose+cast -> wqkv_t[n][k] (96x64 tiles of 32x32)
// blocks [14592,18688): Wo transpose+cast -> wo_t[n][k] (64x64 tiles)
__global__ __launch_bounds__(256) void prep(const float4v* __restrict__ x,
                                            const float* __restrict__ Wq,
                                            const float* __restrict__ Wk,
                                            const float* __restrict__ Wv,
                                            const float* __restrict__ Wo,
                                            ushort4v* __restrict__ xb,
                                            u16* __restrict__ wqkv_t,
                                            u16* __restrict__ wo_t,
                                            float2v* __restrict__ tab) {
    __shared__ float lds[32][33];
    const int bid = blockIdx.x;
    const int tid = threadIdx.x;
    if (bid < 8192) {
        const int i = bid * 256 + tid;
        float4v v = x[i];
        ushort4v o;
        #pragma unroll
        for (int j = 0; j < 4; ++j) o[j] = f2bf(v[j]);
        xb[i] = o;
        return;
    }
    if (bid < 8448) {
        const int idx = (bid - 8192) * 256 + tid;   // 65536
        const int t = idx >> 5;
        const int i = idx & 31;
        const float invf = exp2f(-(float)i * (19.931568569324174f / 32.0f));
        float sv, cv;
        sincosf((float)t * invf, &sv, &cv);
        float2v o; o[0] = cv; o[1] = sv;
        tab[idx] = o;
        return;
    }
    const float* src;
    int Ns, n0, k0, scol0;
    u16* dst;
    if (bid < 14592) {
        const int id = bid - 8448;
        const int bx = id % 96, by = id / 96;
        n0 = bx * 32; k0 = by * 32;
        if (n0 < 2048)      { src = Wq; Ns = 2048; scol0 = n0; }
        else if (n0 < 2560) { src = Wk; Ns = 512;  scol0 = n0 - 2048; }
        else                { src = Wv; Ns = 512;  scol0 = n0 - 2560; }
        dst = wqkv_t;
    } else {
        const int id = bid - 14592;
        const int bx = id & 63, by = id >> 6;
        n0 = bx * 32; k0 = by * 32;
        src = Wo; Ns = 2048; scol0 = n0;
        dst = wo_t;
    }
    const int row = tid >> 3;            // k local
    const int c4  = (tid & 7) * 4;       // n local
    const float4v v = *(const float4v*)(src + (size_t)(k0 + row) * Ns + scol0 + c4);
    #pragma unroll
    for (int i = 0; i < 4; ++i) lds[row][c4 + i] = v[i];
    __syncthreads();
    const int nrow = tid >> 3;           // n local
    const int k4   = (tid & 7) * 4;      // k local
    ushort4v o;
    #pragma unroll
    for (int i = 0; i < 4; ++i) o[i] = f2bf(lds[k4 + i][nrow]);
    *(ushort4v*)(dst + (size_t)(n0 + nrow) * 2048 + k0 + k4) = o;
}

// ---------- 2. plain GEMM (for the output projection): C = A * Bt^T, fp32 out ----------
__global__ __launch_bounds__(256) void gemm_bt(const u16* __restrict__ A,
                                               const u16* __restrict__ Bt,
                                               float* __restrict__ C,
                                               int M, int N, int K) {
    __shared__ u16 lds_a[128 * 32];
    __shared__ u16 lds_b[128 * 32];
    const int tid  = threadIdx.x;
    const int wave = tid >> 6;
    const int lane = tid & 63;
    const int quad = lane >> 4;
    const int l15  = lane & 15;
    const long m0 = (long)blockIdx.x * 128;
    const long n0 = (long)blockIdx.y * 128;
    const int wm = (wave >> 1) * 64;
    const int wn = (wave & 1) * 64;
    const int sa_row = lane >> 2;
    const int sa_col = (lane & 3) * 8;

    float4v acc[4][4];
    #pragma unroll
    for (int i = 0; i < 4; ++i)
        #pragma unroll
        for (int j = 0; j < 4; ++j)
            #pragma unroll
            for (int r = 0; r < 4; ++r) acc[i][j][r] = 0.0f;

    for (int k0 = 0; k0 < K; k0 += 32) {
        #pragma unroll
        for (int i = 0; i < 2; ++i) {
            const int slot = wave * 2 + i;
            const u16* ga = A  + (m0 + slot * 16 + sa_row) * (long)K + k0 + sa_col;
            gload_lds16(ga, lds_a + slot * 512);
            const u16* gb = Bt + (n0 + slot * 16 + sa_row) * (long)K + k0 + sa_col;
            gload_lds16(gb, lds_b + slot * 512);
        }
        __syncthreads();
        short8 af[4], bfr[4];
        #pragma unroll
        for (int mt = 0; mt < 4; ++mt)
            af[mt] = *(const short8*)(lds_a + (wm + mt * 16 + l15) * 32 + quad * 8);
        #pragma unroll
        for (int nt = 0; nt < 4; ++nt)
            bfr[nt] = *(const short8*)(lds_b + (wn + nt * 16 + l15) * 32 + quad * 8);
        #pragma unroll
        for (int mt = 0; mt < 4; ++mt)
            #pragma unroll
            for (int nt = 0; nt < 4; ++nt)
                acc[mt][nt] = __builtin_amdgcn_mfma_f32_16x16x32_bf16(af[mt], bfr[nt], acc[mt][nt], 0, 0, 0);
        __syncthreads();
    }
    #pragma unroll
    for (int mt = 0; mt < 4; ++mt) {
        #pragma unroll
        for (int nt = 0; nt < 4; ++nt) {
            const long gr = m0 + wm + mt * 16 + quad * 4;
            const long gc = n0 + wn + nt * 16 + l15;
            #pragma unroll
            for (int r = 0; r < 4; ++r)
                C[(gr + r) * N + gc] = acc[mt][nt][r];
        }
    }
}

// ---------- 3. QKV GEMM with fused RMSNorm + RoPE + V-transpose epilogue ----------
// C rows = tokens (b*2048+t), cols: [0,2048) Q heads, [2048,2560) K heads,
// [2560,3072) V heads. Each wave's 64-col strip is exactly one head.
// Q/K: row Σv² via 4 intra-quad shuffles; RoPE pair (d,d+32) = (nt,nt+2) same
// lane; cos/sin from table. Q gets 0.125*log2(e) folded. V: write transposed
// [head][d][t]. Outputs land directly in q_r/k_r/v_r — no qkv intermediate.
__global__ __launch_bounds__(256) void gemm_qkv(const u16* __restrict__ A,
                                                const u16* __restrict__ Bt,
                                                const float* __restrict__ qw,
                                                const float* __restrict__ kw,
                                                const float2v* __restrict__ tab,
                                                u16* __restrict__ Qr,
                                                u16* __restrict__ Kr,
                                                u16* __restrict__ Vt) {
    const int K = 2048;
    __shared__ u16 lds_a[128 * 32];
    __shared__ u16 lds_b[128 * 32];
    const int tid  = threadIdx.x;
    const int wave = tid >> 6;
    const int lane = tid & 63;
    const int quad = lane >> 4;
    const int l15  = lane & 15;
    const long m0 = (long)blockIdx.x * 128;
    const long n0 = (long)blockIdx.y * 128;
    const int wm = (wave >> 1) * 64;
    const int wn = (wave & 1) * 64;
    const int sa_row = lane >> 2;
    const int sa_col = (lane & 3) * 8;

    float4v acc[4][4];
    #pragma unroll
    for (int i = 0; i < 4; ++i)
        #pragma unroll
        for (int j = 0; j < 4; ++j)
            #pragma unroll
            for (int r = 0; r < 4; ++r) acc[i][j][r] = 0.0f;

    for (int k0 = 0; k0 < K; k0 += 32) {
        #pragma unroll
        for (int i = 0; i < 2; ++i) {
            const int slot = wave * 2 + i;
            const u16* ga = A  + (m0 + slot * 16 + sa_row) * (long)K + k0 + sa_col;
            gload_lds16(ga, lds_a + slot * 512);
            const u16* gb = Bt + (n0 + slot * 16 + sa_row) * (long)K + k0 + sa_col;
            gload_lds16(gb, lds_b + slot * 512);
        }
        __syncthreads();
        short8 af[4], bfr[4];
        #pragma unroll
        for (int mt = 0; mt < 4; ++mt)
            af[mt] = *(const short8*)(lds_a + (wm + mt * 16 + l15) * 32 + quad * 8);
        #pragma unroll
        for (int nt = 0; nt < 4; ++nt)
            bfr[nt] = *(const short8*)(lds_b + (wn + nt * 16 + l15) * 32 + quad * 8);
        #pragma unroll
        for (int mt = 0; mt < 4; ++mt)
            #pragma unroll
            for (int nt = 0; nt < 4; ++nt)
                acc[mt][nt] = __builtin_amdgcn_mfma_f32_16x16x32_bf16(af[mt], bfr[nt], acc[mt][nt], 0, 0, 0);
        __syncthreads();
    }

    const int col0 = (int)n0 + wn;          // 64-aligned; whole wave in one zone
    if (col0 < 2560) {
        // ---- Q or K head: RMSNorm + RoPE ----
        const bool isQ = (col0 < 2048);
        const float* lw = isQ ? qw : kw;
        float wreg[4];
        #pragma unroll
        for (int nt = 0; nt < 4; ++nt) wreg[nt] = lw[nt * 16 + l15];
        const float qs = isQ ? 0.18033688011112042f : 1.0f;   // 0.125*log2(e) for Q
        u16* dst = isQ ? (Qr + ((size_t)(col0 >> 6)) * 2048 * 64)
                       : (Kr + ((size_t)((col0 - 2048) >> 6)) * 2048 * 64);
        const size_t head_stride = isQ ? ((size_t)32 * 2048 * 64) : ((size_t)8 * 2048 * 64);
        #pragma unroll
        for (int mt = 0; mt < 4; ++mt) {
            const int gr0 = (int)m0 + wm + mt * 16 + quad * 4;
            const int b = gr0 >> 11, tt0 = gr0 & 2047;
            float rms[4];
            #pragma unroll
            for (int r = 0; r < 4; ++r) {
                float s = 0.0f;
                #pragma unroll
                for (int nt = 0; nt < 4; ++nt) s += acc[mt][nt][r] * acc[mt][nt][r];
                s += __shfl_xor(s, 1);
                s += __shfl_xor(s, 2);
                s += __shfl_xor(s, 4);
                s += __shfl_xor(s, 8);
                rms[r] = rsqrtf(s * (1.0f / 64.0f) + 1e-5f);
            }
            u16* rowp = dst + (size_t)b * head_stride + (size_t)tt0 * 64;
            #pragma unroll
            for (int nt = 0; nt < 2; ++nt) {
                const int i = nt * 16 + l15;
                #pragma unroll
                for (int r = 0; r < 4; ++r) {
                    const float2v cs = tab[(tt0 + r) * 32 + i];
                    const float v1 = acc[mt][nt][r]     * rms[r] * wreg[nt];
                    const float v2 = acc[mt][nt + 2][r] * rms[r] * wreg[nt + 2];
                    const float o1 = (v1 * cs[0] - v2 * cs[1]) * qs;
                    const float o2 = (v2 * cs[0] + v1 * cs[1]) * qs;
                    rowp[(size_t)r * 64 + i]      = f2bf(o1);
                    rowp[(size_t)r * 64 + i + 32] = f2bf(o2);
                }
            }
        }
    } else {
        // ---- V head: transpose to [head][d][t] ----
        const int kh = (col0 - 2560) >> 6;
        #pragma unroll
        for (int mt = 0; mt < 4; ++mt) {
            const int gr0 = (int)m0 + wm + mt * 16 + quad * 4;
            const int b = gr0 >> 11, tt0 = gr0 & 2047;
            #pragma unroll
            for (int nt = 0; nt < 4; ++nt) {
                const int d = nt * 16 + l15;
                ushort4v o;
                #pragma unroll
                for (int r = 0; r < 4; ++r) o[r] = f2bf(acc[mt][nt][r]);
                *(ushort4v*)(Vt + (((size_t)(b * 8 + kh)) * 64 + d) * 2048 + tt0) = o;
            }
        }
    }
}

// ---------- 4. flash attention: folded causal triangle + LDS double-buffer ----------
#define KSTR 72    // lds_k row stride (pad 64->72)
#define VSTR 136   // lds_vt row stride (pad 128->136)
__global__ __launch_bounds__(512, 4) void attn_fwd(const u16* __restrict__ Qr,
                                                   const u16* __restrict__ Kr,
                                                   const u16* __restrict__ Vt,
                                                   u16* __restrict__ Ob) {
    __shared__ u16 lds_k[2][128 * KSTR];
    __shared__ u16 lds_vt[2][64 * VSTR];
    const int tid  = threadIdx.x;
    const int wave = tid >> 6;              // 0..7
    const int lane = tid & 63;
    const int quad = lane >> 4;
    const int l15  = lane & 15;
    const int qxB = blockIdx.x;             // 0..7
    const int qxA = 15 - qxB;               // 15..8
    const int bh = blockIdx.y;              // 0..63
    const int b = bh >> 5, h = bh & 31;
    const int kh = h >> 2;
    const u16* Qh = Qr + ((size_t)(b * 32 + h))  * 2048 * 64;
    const u16* Kh = Kr + ((size_t)(b * 8 + kh))  * 2048 * 64;
    const u16* Vh = Vt + ((size_t)(b * 8 + kh))  * 64 * 2048;

    const int k_key0 = tid >> 3;
    const int k_d0   = (tid & 7) * 8;
    const int v_d0   = tid >> 4;
    const int v_k8   = (tid & 15) * 8;

    const int qrowA = qxA * 128 + wave * 16 + l15;
    const int qrowB = qxB * 128 + wave * 16 + l15;
    short8 qfA[2], qfB[2];
    #pragma unroll
    for (int ks = 0; ks < 2; ++ks) {
        qfA[ks] = *(const short8*)(Qh + (size_t)qrowA * 64 + ks * 32 + quad * 8);
        qfB[ks] = *(const short8*)(Qh + (size_t)qrowB * 64 + ks * 32 + quad * 8);
    }
    short8 qf0 = qfA[0], qf1 = qfA[1];
    int qrow_cur = qrowA;

    float m_i = -3e38f, l_i = 0.0f;
    float4v Oacc[4];
    #pragma unroll
    for (int dt = 0; dt < 4; ++dt)
        #pragma unroll
        for (int r = 0; r < 4; ++r) Oacc[dt][r] = 0.0f;

    short8 kreg[2], vreg[2];
    #pragma unroll
    for (int i = 0; i < 2; ++i) {
        kreg[i] = *(const short8*)(Kh + (size_t)(k_key0 + i * 64) * 64 + k_d0);
        vreg[i] = *(const short8*)(Vh + (size_t)(v_d0 + i * 32) * 2048 + v_k8);
    }
    #pragma unroll
    for (int i = 0; i < 2; ++i) {
        *(short8*)(lds_k[0]  + (k_key0 + i * 64) * KSTR + k_d0) = kreg[i];
        *(short8*)(lds_vt[0] + (v_d0 + i * 32) * VSTR + v_k8)   = vreg[i];
    }
    __syncthreads();

    const int n_it = 17;
    for (int i = 0; i < n_it; ++i) {
        const int p = i & 1;
        const bool last = (i == n_it - 1);
        const int kt_cur = (i <= qxA) ? i : (i - qxA - 1);
        const int kt0 = kt_cur << 7;

        if (!last) {
            const int ip1 = i + 1;
            const int ktn = (ip1 <= qxA) ? ip1 : (ip1 - qxA - 1);
            const size_t nk0 = (size_t)(ktn << 7);
            #pragma unroll
            for (int j = 0; j < 2; ++j) {
                kreg[j] = *(const short8*)(Kh + (nk0 + k_key0 + j * 64) * 64 + k_d0);
                vreg[j] = *(const short8*)(Vh + (size_t)(v_d0 + j * 32) * 2048 + nk0 + v_k8);
            }
        }

        float4v S[8];
        #pragma unroll
        for (int nt = 0; nt < 8; ++nt)
            #pragma unroll
            for (int r = 0; r < 4; ++r) S[nt][r] = 0.0f;
        #pragma unroll
        for (int ks = 0; ks < 2; ++ks) {
            const short8 qf = ks ? qf1 : qf0;
            #pragma unroll
            for (int nt = 0; nt < 8; ++nt) {
                short8 kf = *(const short8*)(lds_k[p] + (nt * 16 + l15) * KSTR + ks * 32 + quad * 8);
                S[nt] = __builtin_amdgcn_mfma_f32_16x16x32_bf16(kf, qf, S[nt], 0, 0, 0);
            }
        }
        if (i == qxA || last) {
            #pragma unroll
            for (int nt = 0; nt < 8; ++nt) {
                const int keyb = kt0 + nt * 16 + quad * 4;
                #pragma unroll
                for (int r = 0; r < 4; ++r)
                    if (keyb + r > qrow_cur) S[nt][r] = -3e38f;
            }
        }
        float mx = S[0][0];
        #pragma unroll
        for (int nt = 0; nt < 8; ++nt)
            #pragma unroll
            for (int r = 0; r < 4; ++r) mx = fmaxf(mx, S[nt][r]);
        mx = fmaxf(mx, __shfl_xor(mx, 16));
        mx = fmaxf(mx, __shfl_xor(mx, 32));
        const float mnew = fmaxf(m_i, mx);
        const float alpha = __builtin_amdgcn_exp2f(m_i - mnew);
        m_i = mnew;
        float rs = 0.0f;
        #pragma unroll
        for (int nt = 0; nt < 8; ++nt)
            #pragma unroll
            for (int r = 0; r < 4; ++r) {
                const float pv = __builtin_amdgcn_exp2f(S[nt][r] - mnew);
                S[nt][r] = pv;
                rs += pv;
            }
        rs += __shfl_xor(rs, 16);
        rs += __shfl_xor(rs, 32);
        l_i = l_i * alpha + rs;
        #pragma unroll
        for (int dt = 0; dt < 4; ++dt)
            #pragma unroll
            for (int r = 0; r < 4; ++r) Oacc[dt][r] *= alpha;

        #pragma unroll
        for (int nt = 0; nt < 8; ++nt) {
            union { uint32_t u[2]; short4v s; } pu;
            pu.u[0] = pack_bf16x2(S[nt][0], S[nt][1]);
            pu.u[1] = pack_bf16x2(S[nt][2], S[nt][3]);
            const short4v pf = pu.s;
            #pragma unroll
            for (int dt = 0; dt < 4; ++dt) {
                const short4v vf = *(const short4v*)(lds_vt[p] + (dt * 16 + l15) * VSTR + nt * 16 + quad * 4);
                Oacc[dt] = __builtin_amdgcn_mfma_f32_16x16x16bf16_1k(vf, pf, Oacc[dt], 0, 0, 0);
            }
        }

        if (i == qxA) {
            const float rl = 1.0f / l_i;
            #pragma unroll
            for (int dt = 0; dt < 4; ++dt) {
                ushort4v o;
                #pragma unroll
                for (int r = 0; r < 4; ++r) o[r] = f2bf(Oacc[dt][r] * rl);
                *(ushort4v*)(Ob + ((size_t)(b * 2048 + qrowA)) * 2048 + h * 64 + dt * 16 + quad * 4) = o;
            }
            m_i = -3e38f;
            l_i = 0.0f;
            qf0 = qfB[0];
            qf1 = qfB[1];
            qrow_cur = qrowB;
        }

        if (!last) {
            #pragma unroll
            for (int j = 0; j < 2; ++j) {
                *(short8*)(lds_k[1 - p]  + (k_key0 + j * 64) * KSTR + k_d0) = kreg[j];
                *(short8*)(lds_vt[1 - p] + (v_d0 + j * 32) * VSTR + v_k8)   = vreg[j];
            }
        }
        __syncthreads();
    }
    const float rl = 1.0f / l_i;
    #pragma unroll
    for (int dt = 0; dt < 4; ++dt) {
        ushort4v o;
        #pragma unroll
        for (int r = 0; r < 4; ++r) o[r] = f2bf(Oacc[dt][r] * rl);
        *(ushort4v*)(Ob + ((size_t)(b * 2048 + qrowB)) * 2048 + h * 64 + dt * 16 + quad * 4) = o;
    }
}

// ---------- launcher ----------
extern "C" void kernel_launch(void* const* d_in, const int* in_sizes, int n_in,
                              void* d_out, int out_size, void* d_ws, size_t ws_size,
                              hipStream_t stream) {
    (void)in_sizes; (void)n_in; (void)out_size; (void)ws_size;
    const float* x  = (const float*)d_in[0];
    const float* Wq = (const float*)d_in[1];
    const float* Wk = (const float*)d_in[2];
    const float* Wv = (const float*)d_in[3];
    const float* Wo = (const float*)d_in[4];
    const float* qw = (const float*)d_in[5];
    const float* kw = (const float*)d_in[6];
    float* out = (float*)d_out;

    char* ws = (char*)d_ws;
    size_t off = 0;
    auto alloc = [&](size_t bytes) {
        char* p = ws + off;
        off += (bytes + 255) & ~(size_t)255;
        return p;
    };
    u16* xb     = (u16*)alloc((size_t)8388608 * 2);        // x bf16       16 MB
    u16* wqkv_t = (u16*)alloc((size_t)3072 * 2048 * 2);    // [n][k]       12 MB
    u16* wo_t   = (u16*)alloc((size_t)2048 * 2048 * 2);    //               8 MB
    u16* q_r    = (u16*)alloc((size_t)2 * 32 * 2048 * 64 * 2);  // 16 MB
    u16* k_r    = (u16*)alloc((size_t)2 * 8 * 2048 * 64 * 2);   //  4 MB
    u16* v_r    = (u16*)alloc((size_t)2 * 8 * 64 * 2048 * 2);   //  4 MB (d-major)
    float2v* rtab = (float2v*)alloc((size_t)2048 * 32 * 8);     // 512 KB
    u16* attnb  = xb;   // reuse: xb dead after gemm_qkv

    hipLaunchKernelGGL(prep, dim3(18688), dim3(256), 0, stream,
                       (const float4v*)x, Wq, Wk, Wv, Wo,
                       (ushort4v*)xb, wqkv_t, wo_t, rtab);
    hipLaunchKernelGGL(gemm_qkv, dim3(32, 24), dim3(256), 0, stream,
                       xb, wqkv_t, qw, kw, rtab, q_r, k_r, v_r);
    hipLaunchKernelGGL(attn_fwd, dim3(8, 64), dim3(512), 0, stream, q_r, k_r, v_r, attnb);
    hipLaunchKernelGGL(gemm_bt, dim3(32, 16), dim3(256), 0, stream,
                       attnb, wo_t, out, 4096, 2048, 2048);
}

// Round 6
// 299.745 us; speedup vs baseline: 1.5596x; 1.1045x over previous
//
#include <hip/hip_runtime.h>
#include <cstdint>
#include <cstddef>

typedef unsigned short u16;
typedef __attribute__((ext_vector_type(8))) short short8;    // 8 bf16 (4 VGPRs) MFMA A/B frag (x32)
typedef __attribute__((ext_vector_type(4))) short short4v;   // 4 bf16 (2 VGPRs) MFMA A/B frag (x16)
typedef __attribute__((ext_vector_type(4))) float float4v;   // MFMA C/D frag
typedef __attribute__((ext_vector_type(4))) unsigned short ushort4v;
typedef __attribute__((ext_vector_type(2))) float float2v;

// ---------- helpers ----------
__device__ __forceinline__ u16 f2bf(float f) {
    union { float f; uint32_t u; } x; x.f = f;
    uint32_t r = x.u + 0x7fffu + ((x.u >> 16) & 1u);   // RTNE
    return (u16)(r >> 16);
}
// pack two fp32 -> two bf16 in one dword
__device__ __forceinline__ uint32_t pack_bf16x2(float lo, float hi) {
    union { float f; uint32_t u; } a, b; a.f = lo; b.f = hi;
    return __builtin_amdgcn_perm(b.u + 0x8000u, a.u + 0x8000u, 0x07060302u);
}

// ---------- 1. merged prep: cast x, rope table, weight transposes ----------
__global__ __launch_bounds__(256) void prep(const float4v* __restrict__ x,
                                            const float* __restrict__ Wq,
                                            const float* __restrict__ Wk,
                                            const float* __restrict__ Wv,
                                            const float* __restrict__ Wo,
                                            ushort4v* __restrict__ xb,
                                            u16* __restrict__ wqkv_t,
                                            u16* __restrict__ wo_t,
                                            float2v* __restrict__ tab) {
    __shared__ float lds[32][33];
    const int bid = blockIdx.x;
    const int tid = threadIdx.x;
    if (bid < 8192) {
        const int i = bid * 256 + tid;
        float4v v = x[i];
        ushort4v o;
        #pragma unroll
        for (int j = 0; j < 4; ++j) o[j] = f2bf(v[j]);
        xb[i] = o;
        return;
    }
    if (bid < 8448) {
        const int idx = (bid - 8192) * 256 + tid;   // 65536
        const int t = idx >> 5;
        const int i = idx & 31;
        const float invf = exp2f(-(float)i * (19.931568569324174f / 32.0f));
        float sv, cv;
        sincosf((float)t * invf, &sv, &cv);
        float2v o; o[0] = cv; o[1] = sv;
        tab[idx] = o;
        return;
    }
    const float* src;
    int Ns, n0, k0, scol0;
    u16* dst;
    if (bid < 14592) {
        const int id = bid - 8448;
        const int bx = id % 96, by = id / 96;
        n0 = bx * 32; k0 = by * 32;
        if (n0 < 2048)      { src = Wq; Ns = 2048; scol0 = n0; }
        else if (n0 < 2560) { src = Wk; Ns = 512;  scol0 = n0 - 2048; }
        else                { src = Wv; Ns = 512;  scol0 = n0 - 2560; }
        dst = wqkv_t;
    } else {
        const int id = bid - 14592;
        const int bx = id & 63, by = id >> 6;
        n0 = bx * 32; k0 = by * 32;
        src = Wo; Ns = 2048; scol0 = n0;
        dst = wo_t;
    }
    const int row = tid >> 3;            // k local
    const int c4  = (tid & 7) * 4;       // n local
    const float4v v = *(const float4v*)(src + (size_t)(k0 + row) * Ns + scol0 + c4);
    #pragma unroll
    for (int i = 0; i < 4; ++i) lds[row][c4 + i] = v[i];
    __syncthreads();
    const int nrow = tid >> 3;           // n local
    const int k4   = (tid & 7) * 4;      // k local
    ushort4v o;
    #pragma unroll
    for (int i = 0; i < 4; ++i) o[i] = f2bf(lds[k4 + i][nrow]);
    *(ushort4v*)(dst + (size_t)(n0 + nrow) * 2048 + k0 + k4) = o;
}

// ---------- 2. output-projection GEMM, software-pipelined ----------
// 128x128 tile, BK=32, LDS double-buffer: register-prefetch tile k+1 at top
// of iter (latency overlapped by MFMAs), ds_write to other buffer, ONE
// barrier per K-iter. No global_load_lds -> no vmcnt(0) drain at barrier.
__global__ __launch_bounds__(256, 3) void gemm_bt(const u16* __restrict__ A,
                                                  const u16* __restrict__ Bt,
                                                  float* __restrict__ C,
                                                  int M, int N, int K) {
    __shared__ u16 lds_a[2][128 * 32];
    __shared__ u16 lds_b[2][128 * 32];
    const int tid  = threadIdx.x;
    const int wave = tid >> 6;
    const int lane = tid & 63;
    const int quad = lane >> 4;
    const int l15  = lane & 15;
    const long m0 = (long)blockIdx.x * 128;
    const long n0 = (long)blockIdx.y * 128;
    const int wm = (wave >> 1) * 64;
    const int wn = (wave & 1) * 64;
    const int s_row = tid >> 2;           // 0..63 (chunk c adds c*64)
    const int s_col = (tid & 3) * 8;      // 0,8,16,24

    float4v acc[4][4];
    #pragma unroll
    for (int i = 0; i < 4; ++i)
        #pragma unroll
        for (int j = 0; j < 4; ++j)
            #pragma unroll
            for (int r = 0; r < 4; ++r) acc[i][j][r] = 0.0f;

    short8 areg[2], breg[2];
    #pragma unroll
    for (int c = 0; c < 2; ++c) {
        areg[c] = *(const short8*)(A  + (m0 + c * 64 + s_row) * (long)K + s_col);
        breg[c] = *(const short8*)(Bt + (n0 + c * 64 + s_row) * (long)K + s_col);
    }
    #pragma unroll
    for (int c = 0; c < 2; ++c) {
        *(short8*)(lds_a[0] + (c * 64 + s_row) * 32 + s_col) = areg[c];
        *(short8*)(lds_b[0] + (c * 64 + s_row) * 32 + s_col) = breg[c];
    }
    __syncthreads();

    const int n_k = K >> 5;
    for (int it = 0; it < n_k; ++it) {
        const int p = it & 1;
        if (it + 1 < n_k) {
            const int kn = (it + 1) << 5;
            #pragma unroll
            for (int c = 0; c < 2; ++c) {
                areg[c] = *(const short8*)(A  + (m0 + c * 64 + s_row) * (long)K + kn + s_col);
                breg[c] = *(const short8*)(Bt + (n0 + c * 64 + s_row) * (long)K + kn + s_col);
            }
        }
        short8 af[4], bfr[4];
        #pragma unroll
        for (int mt = 0; mt < 4; ++mt)
            af[mt] = *(const short8*)(lds_a[p] + (wm + mt * 16 + l15) * 32 + quad * 8);
        #pragma unroll
        for (int nt = 0; nt < 4; ++nt)
            bfr[nt] = *(const short8*)(lds_b[p] + (wn + nt * 16 + l15) * 32 + quad * 8);
        #pragma unroll
        for (int mt = 0; mt < 4; ++mt)
            #pragma unroll
            for (int nt = 0; nt < 4; ++nt)
                acc[mt][nt] = __builtin_amdgcn_mfma_f32_16x16x32_bf16(af[mt], bfr[nt], acc[mt][nt], 0, 0, 0);
        if (it + 1 < n_k) {
            #pragma unroll
            for (int c = 0; c < 2; ++c) {
                *(short8*)(lds_a[1 - p] + (c * 64 + s_row) * 32 + s_col) = areg[c];
                *(short8*)(lds_b[1 - p] + (c * 64 + s_row) * 32 + s_col) = breg[c];
            }
        }
        __syncthreads();
    }
    #pragma unroll
    for (int mt = 0; mt < 4; ++mt) {
        #pragma unroll
        for (int nt = 0; nt < 4; ++nt) {
            const long gr = m0 + wm + mt * 16 + quad * 4;
            const long gc = n0 + wn + nt * 16 + l15;
            #pragma unroll
            for (int r = 0; r < 4; ++r)
                C[(gr + r) * N + gc] = acc[mt][nt][r];
        }
    }
}

// ---------- 3. QKV GEMM, software-pipelined, fused RMSNorm+RoPE+V-transpose ----------
__global__ __launch_bounds__(256, 3) void gemm_qkv(const u16* __restrict__ A,
                                                   const u16* __restrict__ Bt,
                                                   const float* __restrict__ qw,
                                                   const float* __restrict__ kw,
                                                   const float2v* __restrict__ tab,
                                                   u16* __restrict__ Qr,
                                                   u16* __restrict__ Kr,
                                                   u16* __restrict__ Vt) {
    const int K = 2048;
    __shared__ u16 lds_a[2][128 * 32];
    __shared__ u16 lds_b[2][128 * 32];
    const int tid  = threadIdx.x;
    const int wave = tid >> 6;
    const int lane = tid & 63;
    const int quad = lane >> 4;
    const int l15  = lane & 15;
    const long m0 = (long)blockIdx.x * 128;
    const long n0 = (long)blockIdx.y * 128;
    const int wm = (wave >> 1) * 64;
    const int wn = (wave & 1) * 64;
    const int s_row = tid >> 2;
    const int s_col = (tid & 3) * 8;

    float4v acc[4][4];
    #pragma unroll
    for (int i = 0; i < 4; ++i)
        #pragma unroll
        for (int j = 0; j < 4; ++j)
            #pragma unroll
            for (int r = 0; r < 4; ++r) acc[i][j][r] = 0.0f;

    short8 areg[2], breg[2];
    #pragma unroll
    for (int c = 0; c < 2; ++c) {
        areg[c] = *(const short8*)(A  + (m0 + c * 64 + s_row) * (long)K + s_col);
        breg[c] = *(const short8*)(Bt + (n0 + c * 64 + s_row) * (long)K + s_col);
    }
    #pragma unroll
    for (int c = 0; c < 2; ++c) {
        *(short8*)(lds_a[0] + (c * 64 + s_row) * 32 + s_col) = areg[c];
        *(short8*)(lds_b[0] + (c * 64 + s_row) * 32 + s_col) = breg[c];
    }
    __syncthreads();

    const int n_k = K >> 5;   // 64
    for (int it = 0; it < n_k; ++it) {
        const int p = it & 1;
        if (it + 1 < n_k) {
            const int kn = (it + 1) << 5;
            #pragma unroll
            for (int c = 0; c < 2; ++c) {
                areg[c] = *(const short8*)(A  + (m0 + c * 64 + s_row) * (long)K + kn + s_col);
                breg[c] = *(const short8*)(Bt + (n0 + c * 64 + s_row) * (long)K + kn + s_col);
            }
        }
        short8 af[4], bfr[4];
        #pragma unroll
        for (int mt = 0; mt < 4; ++mt)
            af[mt] = *(const short8*)(lds_a[p] + (wm + mt * 16 + l15) * 32 + quad * 8);
        #pragma unroll
        for (int nt = 0; nt < 4; ++nt)
            bfr[nt] = *(const short8*)(lds_b[p] + (wn + nt * 16 + l15) * 32 + quad * 8);
        #pragma unroll
        for (int mt = 0; mt < 4; ++mt)
            #pragma unroll
            for (int nt = 0; nt < 4; ++nt)
                acc[mt][nt] = __builtin_amdgcn_mfma_f32_16x16x32_bf16(af[mt], bfr[nt], acc[mt][nt], 0, 0, 0);
        if (it + 1 < n_k) {
            #pragma unroll
            for (int c = 0; c < 2; ++c) {
                *(short8*)(lds_a[1 - p] + (c * 64 + s_row) * 32 + s_col) = areg[c];
                *(short8*)(lds_b[1 - p] + (c * 64 + s_row) * 32 + s_col) = breg[c];
            }
        }
        __syncthreads();
    }

    const int col0 = (int)n0 + wn;          // 64-aligned; whole wave in one zone
    if (col0 < 2560) {
        // ---- Q or K head: RMSNorm + RoPE ----
        const bool isQ = (col0 < 2048);
        const float* lw = isQ ? qw : kw;
        float wreg[4];
        #pragma unroll
        for (int nt = 0; nt < 4; ++nt) wreg[nt] = lw[nt * 16 + l15];
        const float qs = isQ ? 0.18033688011112042f : 1.0f;   // 0.125*log2(e) for Q
        u16* dst = isQ ? (Qr + ((size_t)(col0 >> 6)) * 2048 * 64)
                       : (Kr + ((size_t)((col0 - 2048) >> 6)) * 2048 * 64);
        const size_t head_stride = isQ ? ((size_t)32 * 2048 * 64) : ((size_t)8 * 2048 * 64);
        #pragma unroll
        for (int mt = 0; mt < 4; ++mt) {
            const int gr0 = (int)m0 + wm + mt * 16 + quad * 4;
            const int b = gr0 >> 11, tt0 = gr0 & 2047;
            float rms[4];
            #pragma unroll
            for (int r = 0; r < 4; ++r) {
                float s = 0.0f;
                #pragma unroll
                for (int nt = 0; nt < 4; ++nt) s += acc[mt][nt][r] * acc[mt][nt][r];
                s += __shfl_xor(s, 1);
                s += __shfl_xor(s, 2);
                s += __shfl_xor(s, 4);
                s += __shfl_xor(s, 8);
                rms[r] = rsqrtf(s * (1.0f / 64.0f) + 1e-5f);
            }
            u16* rowp = dst + (size_t)b * head_stride + (size_t)tt0 * 64;
            #pragma unroll
            for (int nt = 0; nt < 2; ++nt) {
                const int i = nt * 16 + l15;
                #pragma unroll
                for (int r = 0; r < 4; ++r) {
                    const float2v cs = tab[(tt0 + r) * 32 + i];
                    const float v1 = acc[mt][nt][r]     * rms[r] * wreg[nt];
                    const float v2 = acc[mt][nt + 2][r] * rms[r] * wreg[nt + 2];
                    const float o1 = (v1 * cs[0] - v2 * cs[1]) * qs;
                    const float o2 = (v2 * cs[0] + v1 * cs[1]) * qs;
                    rowp[(size_t)r * 64 + i]      = f2bf(o1);
                    rowp[(size_t)r * 64 + i + 32] = f2bf(o2);
                }
            }
        }
    } else {
        // ---- V head: transpose to [head][d][t] ----
        const int kh = (col0 - 2560) >> 6;
        #pragma unroll
        for (int mt = 0; mt < 4; ++mt) {
            const int gr0 = (int)m0 + wm + mt * 16 + quad * 4;
            const int b = gr0 >> 11, tt0 = gr0 & 2047;
            #pragma unroll
            for (int nt = 0; nt < 4; ++nt) {
                const int d = nt * 16 + l15;
                ushort4v o;
                #pragma unroll
                for (int r = 0; r < 4; ++r) o[r] = f2bf(acc[mt][nt][r]);
                *(ushort4v*)(Vt + (((size_t)(b * 8 + kh)) * 64 + d) * 2048 + tt0) = o;
            }
        }
    }
}

// ---------- 4. flash attention: folded causal triangle + LDS double-buffer ----------
#define KSTR 72    // lds_k row stride (pad 64->72)
#define VSTR 136   // lds_vt row stride (pad 128->136)
__global__ __launch_bounds__(512, 4) void attn_fwd(const u16* __restrict__ Qr,
                                                   const u16* __restrict__ Kr,
                                                   const u16* __restrict__ Vt,
                                                   u16* __restrict__ Ob) {
    __shared__ u16 lds_k[2][128 * KSTR];
    __shared__ u16 lds_vt[2][64 * VSTR];
    const int tid  = threadIdx.x;
    const int wave = tid >> 6;              // 0..7
    const int lane = tid & 63;
    const int quad = lane >> 4;
    const int l15  = lane & 15;
    const int qxB = blockIdx.x;             // 0..7
    const int qxA = 15 - qxB;               // 15..8
    const int bh = blockIdx.y;              // 0..63
    const int b = bh >> 5, h = bh & 31;
    const int kh = h >> 2;
    const u16* Qh = Qr + ((size_t)(b * 32 + h))  * 2048 * 64;
    const u16* Kh = Kr + ((size_t)(b * 8 + kh))  * 2048 * 64;
    const u16* Vh = Vt + ((size_t)(b * 8 + kh))  * 64 * 2048;

    const int k_key0 = tid >> 3;
    const int k_d0   = (tid & 7) * 8;
    const int v_d0   = tid >> 4;
    const int v_k8   = (tid & 15) * 8;

    const int qrowA = qxA * 128 + wave * 16 + l15;
    const int qrowB = qxB * 128 + wave * 16 + l15;
    short8 qfA[2], qfB[2];
    #pragma unroll
    for (int ks = 0; ks < 2; ++ks) {
        qfA[ks] = *(const short8*)(Qh + (size_t)qrowA * 64 + ks * 32 + quad * 8);
        qfB[ks] = *(const short8*)(Qh + (size_t)qrowB * 64 + ks * 32 + quad * 8);
    }
    short8 qf0 = qfA[0], qf1 = qfA[1];
    int qrow_cur = qrowA;

    float m_i = -3e38f, l_i = 0.0f;
    float4v Oacc[4];
    #pragma unroll
    for (int dt = 0; dt < 4; ++dt)
        #pragma unroll
        for (int r = 0; r < 4; ++r) Oacc[dt][r] = 0.0f;

    short8 kreg[2], vreg[2];
    #pragma unroll
    for (int i = 0; i < 2; ++i) {
        kreg[i] = *(const short8*)(Kh + (size_t)(k_key0 + i * 64) * 64 + k_d0);
        vreg[i] = *(const short8*)(Vh + (size_t)(v_d0 + i * 32) * 2048 + v_k8);
    }
    #pragma unroll
    for (int i = 0; i < 2; ++i) {
        *(short8*)(lds_k[0]  + (k_key0 + i * 64) * KSTR + k_d0) = kreg[i];
        *(short8*)(lds_vt[0] + (v_d0 + i * 32) * VSTR + v_k8)   = vreg[i];
    }
    __syncthreads();

    const int n_it = 17;
    for (int i = 0; i < n_it; ++i) {
        const int p = i & 1;
        const bool last = (i == n_it - 1);
        const int kt_cur = (i <= qxA) ? i : (i - qxA - 1);
        const int kt0 = kt_cur << 7;

        if (!last) {
            const int ip1 = i + 1;
            const int ktn = (ip1 <= qxA) ? ip1 : (ip1 - qxA - 1);
            const size_t nk0 = (size_t)(ktn << 7);
            #pragma unroll
            for (int j = 0; j < 2; ++j) {
                kreg[j] = *(const short8*)(Kh + (nk0 + k_key0 + j * 64) * 64 + k_d0);
                vreg[j] = *(const short8*)(Vh + (size_t)(v_d0 + j * 32) * 2048 + nk0 + v_k8);
            }
        }

        float4v S[8];
        #pragma unroll
        for (int nt = 0; nt < 8; ++nt)
            #pragma unroll
            for (int r = 0; r < 4; ++r) S[nt][r] = 0.0f;
        #pragma unroll
        for (int ks = 0; ks < 2; ++ks) {
            const short8 qf = ks ? qf1 : qf0;
            #pragma unroll
            for (int nt = 0; nt < 8; ++nt) {
                short8 kf = *(const short8*)(lds_k[p] + (nt * 16 + l15) * KSTR + ks * 32 + quad * 8);
                S[nt] = __builtin_amdgcn_mfma_f32_16x16x32_bf16(kf, qf, S[nt], 0, 0, 0);
            }
        }
        if (i == qxA || last) {
            #pragma unroll
            for (int nt = 0; nt < 8; ++nt) {
                const int keyb = kt0 + nt * 16 + quad * 4;
                #pragma unroll
                for (int r = 0; r < 4; ++r)
                    if (keyb + r > qrow_cur) S[nt][r] = -3e38f;
            }
        }
        float mx = S[0][0];
        #pragma unroll
        for (int nt = 0; nt < 8; ++nt)
            #pragma unroll
            for (int r = 0; r < 4; ++r) mx = fmaxf(mx, S[nt][r]);
        mx = fmaxf(mx, __shfl_xor(mx, 16));
        mx = fmaxf(mx, __shfl_xor(mx, 32));
        const float mnew = fmaxf(m_i, mx);
        const float alpha = __builtin_amdgcn_exp2f(m_i - mnew);
        m_i = mnew;
        float rs = 0.0f;
        #pragma unroll
        for (int nt = 0; nt < 8; ++nt)
            #pragma unroll
            for (int r = 0; r < 4; ++r) {
                const float pv = __builtin_amdgcn_exp2f(S[nt][r] - mnew);
                S[nt][r] = pv;
                rs += pv;
            }
        rs += __shfl_xor(rs, 16);
        rs += __shfl_xor(rs, 32);
        l_i = l_i * alpha + rs;
        #pragma unroll
        for (int dt = 0; dt < 4; ++dt)
            #pragma unroll
            for (int r = 0; r < 4; ++r) Oacc[dt][r] *= alpha;

        #pragma unroll
        for (int nt = 0; nt < 8; ++nt) {
            union { uint32_t u[2]; short4v s; } pu;
            pu.u[0] = pack_bf16x2(S[nt][0], S[nt][1]);
            pu.u[1] = pack_bf16x2(S[nt][2], S[nt][3]);
            const short4v pf = pu.s;
            #pragma unroll
            for (int dt = 0; dt < 4; ++dt) {
                const short4v vf = *(const short4v*)(lds_vt[p] + (dt * 16 + l15) * VSTR + nt * 16 + quad * 4);
                Oacc[dt] = __builtin_amdgcn_mfma_f32_16x16x16bf16_1k(vf, pf, Oacc[dt], 0, 0, 0);
            }
        }

        if (i == qxA) {
            const float rl = 1.0f / l_i;
            #pragma unroll
            for (int dt = 0; dt < 4; ++dt) {
                ushort4v o;
                #pragma unroll
                for (int r = 0; r < 4; ++r) o[r] = f2bf(Oacc[dt][r] * rl);
                *(ushort4v*)(Ob + ((size_t)(b * 2048 + qrowA)) * 2048 + h * 64 + dt * 16 + quad * 4) = o;
            }
            m_i = -3e38f;
            l_i = 0.0f;
            qf0 = qfB[0];
            qf1 = qfB[1];
            qrow_cur = qrowB;
        }

        if (!last) {
            #pragma unroll
            for (int j = 0; j < 2; ++j) {
                *(short8*)(lds_k[1 - p]  + (k_key0 + j * 64) * KSTR + k_d0) = kreg[j];
                *(short8*)(lds_vt[1 - p] + (v_d0 + j * 32) * VSTR + v_k8)   = vreg[j];
            }
        }
        __syncthreads();
    }
    const float rl = 1.0f / l_i;
    #pragma unroll
    for (int dt = 0; dt < 4; ++dt) {
        ushort4v o;
        #pragma unroll
        for (int r = 0; r < 4; ++r) o[r] = f2bf(Oacc[dt][r] * rl);
        *(ushort4v*)(Ob + ((size_t)(b * 2048 + qrowB)) * 2048 + h * 64 + dt * 16 + quad * 4) = o;
    }
}

// ---------- launcher ----------
extern "C" void kernel_launch(void* const* d_in, const int* in_sizes, int n_in,
                              void* d_out, int out_size, void* d_ws, size_t ws_size,
                              hipStream_t stream) {
    (void)in_sizes; (void)n_in; (void)out_size; (void)ws_size;
    const float* x  = (const float*)d_in[0];
    const float* Wq = (const float*)d_in[1];
    const float* Wk = (const float*)d_in[2];
    const float* Wv = (const float*)d_in[3];
    const float* Wo = (const float*)d_in[4];
    const float* qw = (const float*)d_in[5];
    const float* kw = (const float*)d_in[6];
    float* out = (float*)d_out;

    char* ws = (char*)d_ws;
    size_t off = 0;
    auto alloc = [&](size_t bytes) {
        char* p = ws + off;
        off += (bytes + 255) & ~(size_t)255;
        return p;
    };
    u16* xb     = (u16*)alloc((size_t)8388608 * 2);        // x bf16       16 MB
    u16* wqkv_t = (u16*)alloc((size_t)3072 * 2048 * 2);    // [n][k]       12 MB
    u16* wo_t   = (u16*)alloc((size_t)2048 * 2048 * 2);    //               8 MB
    u16* q_r    = (u16*)alloc((size_t)2 * 32 * 2048 * 64 * 2);  // 16 MB
    u16* k_r    = (u16*)alloc((size_t)2 * 8 * 2048 * 64 * 2);   //  4 MB
    u16* v_r    = (u16*)alloc((size_t)2 * 8 * 64 * 2048 * 2);   //  4 MB (d-major)
    float2v* rtab = (float2v*)alloc((size_t)2048 * 32 * 8);     // 512 KB
    u16* attnb  = xb;   // reuse: xb dead after gemm_qkv

    hipLaunchKernelGGL(prep, dim3(18688), dim3(256), 0, stream,
                       (const float4v*)x, Wq, Wk, Wv, Wo,
                       (ushort4v*)xb, wqkv_t, wo_t, rtab);
    hipLaunchKernelGGL(gemm_qkv, dim3(32, 24), dim3(256), 0, stream,
                       xb, wqkv_t, qw, kw, rtab, q_r, k_r, v_r);
    hipLaunchKernelGGL(attn_fwd, dim3(8, 64), dim3(512), 0, stream, q_r, k_r, v_r, attnb);
    hipLaunchKernelGGL(gemm_bt, dim3(32, 16), dim3(256), 0, stream,
                       attnb, wo_t, out, 4096, 2048, 2048);
}